// Round 2
// baseline (4950.897 us; speedup 1.0000x reference)
//
#include <hip/hip_runtime.h>
#include <hip/hip_bf16.h>
#include <math.h>

typedef __hip_bfloat16 bf16;

// ---------- helpers ----------
__device__ __forceinline__ float b2f(bf16 v) { return __bfloat162float(v); }
__device__ __forceinline__ bf16 f2b(float v) { return __float2bfloat16(v); }
__device__ __forceinline__ float bits2f(unsigned int u16) {
    union { unsigned int i; float f; } w; w.i = u16 << 16; return w.f;
}

#define DEPTH 4
#define HEADS 8
#define DHEAD 64
#define DIM 512
#define MLPD 2048
#define RED 128
#define BB 8
#define PP 4
#define NN 256
#define ROWS (BB*PP*NN)          // 8192 tokens
#define XELEMS ((size_t)ROWS*DIM) // 4194304

// ---------- GEMM: C = act(A @ W + bias) [+ res]; A bf16 [M,K], W fp32 [K,N] ----------
#define BM 128
#define BN 128
#define BK 16

template<bool OUT_F32>
__global__ __launch_bounds__(256)
void gemm_kernel(const bf16* __restrict__ A, const float* __restrict__ W,
                 const float* __restrict__ bias, const float* __restrict__ res,
                 void* __restrict__ Cv, int M, int N, int K, int act)
{
    __shared__ float As[BK][BM + 4];
    __shared__ float Bs[BK][BN + 4];
    const int tid = threadIdx.x;
    const int bm = blockIdx.y * BM;
    const int bn = blockIdx.x * BN;
    const int tx = tid & 15;
    const int ty = tid >> 4;

    float acc[8][8] = {};

    const int ar = tid >> 1;          // 0..127 A-tile row
    const int ak = (tid & 1) * 8;     // 0 or 8
    const int br = tid >> 4;          // 0..15 B-tile row
    const int bc = (tid & 15) * 8;    // 0..120

    for (int k0 = 0; k0 < K; k0 += BK) {
        uint4 av = *(const uint4*)(A + (size_t)(bm + ar) * K + k0 + ak);
        unsigned int aw[4] = {av.x, av.y, av.z, av.w};
#pragma unroll
        for (int q = 0; q < 4; ++q) {
            As[ak + 2*q    ][ar] = bits2f(aw[q] & 0xffffu);
            As[ak + 2*q + 1][ar] = bits2f(aw[q] >> 16);
        }
        const float* wrow = W + (size_t)(k0 + br) * N + bn + bc;
        float4 b0 = *(const float4*)(wrow);
        float4 b1 = *(const float4*)(wrow + 4);
        Bs[br][bc+0] = b0.x; Bs[br][bc+1] = b0.y; Bs[br][bc+2] = b0.z; Bs[br][bc+3] = b0.w;
        Bs[br][bc+4] = b1.x; Bs[br][bc+5] = b1.y; Bs[br][bc+6] = b1.z; Bs[br][bc+7] = b1.w;
        __syncthreads();
#pragma unroll
        for (int k = 0; k < BK; ++k) {
            float a[8], b[8];
#pragma unroll
            for (int i = 0; i < 8; ++i) a[i] = As[k][ty*8 + i];
#pragma unroll
            for (int j = 0; j < 8; ++j) b[j] = Bs[k][tx*8 + j];
#pragma unroll
            for (int i = 0; i < 8; ++i)
#pragma unroll
                for (int j = 0; j < 8; ++j)
                    acc[i][j] = fmaf(a[i], b[j], acc[i][j]);
        }
        __syncthreads();
    }

#pragma unroll
    for (int i = 0; i < 8; ++i) {
        const int row = bm + ty*8 + i;
#pragma unroll
        for (int j = 0; j < 8; ++j) {
            const int col = bn + tx*8 + j;
            float v = acc[i][j];
            if (bias) v += bias[col];
            if (act == 1) v = 0.5f * v * (1.0f + erff(v * 0.70710678118f)); // exact gelu
            else if (act == 2) v = 1.0f / (1.0f + __expf(-v));              // sigmoid
            if (res) v += res[(size_t)row * N + col];
            if (OUT_F32) ((float*)Cv)[(size_t)row * N + col] = v;
            else         ((bf16*)Cv)[(size_t)row * N + col] = f2b(v);
        }
    }
}

// ---------- LayerNorm over DIM=512, input fp32, params fp32, output bf16 ----------
__global__ __launch_bounds__(256)
void ln_kernel(const float* __restrict__ x, const float* __restrict__ g,
               const float* __restrict__ b, bf16* __restrict__ y, int rows)
{
    const int wave = threadIdx.x >> 6;
    const int lane = threadIdx.x & 63;
    const int row = blockIdx.x * 4 + wave;
    if (row >= rows) return;
    const float* xr = x + (size_t)row * DIM;
    float v[8]; float s = 0.f, s2 = 0.f;
#pragma unroll
    for (int i = 0; i < 8; ++i) {
        v[i] = xr[lane + 64*i];
        s += v[i]; s2 += v[i]*v[i];
    }
#pragma unroll
    for (int off = 32; off; off >>= 1) { s += __shfl_xor(s, off); s2 += __shfl_xor(s2, off); }
    const float mean = s * (1.f/512.f);
    const float var  = s2 * (1.f/512.f) - mean*mean;
    const float rstd = rsqrtf(var + 1e-5f);
    bf16* yr = y + (size_t)row * DIM;
#pragma unroll
    for (int i = 0; i < 8; ++i) {
        const int d = lane + 64*i;
        yr[d] = f2b((v[i]-mean)*rstd*g[d] + b[d]);
    }
}

// ---------- attention: one block per (b,p,h); thread = query row; online softmax ----------
__global__ __launch_bounds__(256)
void attn_kernel(const bf16* __restrict__ qkv, bf16* __restrict__ out)
{
    __shared__ bf16 Ks[NN][DHEAD];
    __shared__ bf16 Vs[NN][DHEAD];
    const int bp = blockIdx.x >> 3;   // 0..31
    const int h  = blockIdx.x & 7;
    const bf16* base = qkv + (size_t)bp * NN * (3*DIM);
    const int qo = h * DHEAD;
    const int ko = DIM + h * DHEAD;
    const int vo = 2*DIM + h * DHEAD;

    for (int idx = threadIdx.x; idx < NN*DHEAD; idx += 256) {
        const int j = idx >> 6, d = idx & 63;
        Ks[j][d] = base[(size_t)j*(3*DIM) + ko + d];
        Vs[j][d] = base[(size_t)j*(3*DIM) + vo + d];
    }
    __syncthreads();

    const int i = threadIdx.x;
    float q[DHEAD];
#pragma unroll
    for (int d = 0; d < DHEAD; ++d)
        q[d] = b2f(base[(size_t)i*(3*DIM) + qo + d]) * 0.125f; // fold 1/sqrt(64)

    float m = -1e30f, l = 0.f;
    float o[DHEAD] = {};
    for (int j = 0; j < NN; ++j) {
        const unsigned int* Kj = (const unsigned int*)(&Ks[j][0]);
        float s = 0.f;
#pragma unroll
        for (int dd = 0; dd < 32; ++dd) {
            unsigned int w = Kj[dd];
            s = fmaf(q[2*dd],   bits2f(w & 0xffffu), s);
            s = fmaf(q[2*dd+1], bits2f(w >> 16),     s);
        }
        if (s > m) {
            const float alpha = __expf(m - s);
            l *= alpha;
#pragma unroll
            for (int d = 0; d < DHEAD; ++d) o[d] *= alpha;
            m = s;
        }
        const float p = __expf(s - m);
        l += p;
        const unsigned int* Vj = (const unsigned int*)(&Vs[j][0]);
#pragma unroll
        for (int dd = 0; dd < 32; ++dd) {
            unsigned int w = Vj[dd];
            o[2*dd]   = fmaf(p, bits2f(w & 0xffffu), o[2*dd]);
            o[2*dd+1] = fmaf(p, bits2f(w >> 16),     o[2*dd+1]);
        }
    }
    const float inv = 1.0f / l;
    bf16* orow = out + ((size_t)bp*NN + i) * DIM + h*DHEAD;
#pragma unroll
    for (int d = 0; d < DHEAD; ++d) orow[d] = f2b(o[d] * inv);
}

// ---------- mean over P of LN'd x: [b,p,n,d] -> [b,n,d] ----------
__global__ void mean_kernel(const bf16* __restrict__ L, bf16* __restrict__ G)
{
    const int idx = blockIdx.x * 256 + threadIdx.x;  // < 8*256*512
    const int b = idx >> 17;
    const int rem = idx & 131071;
    float s = 0.f;
#pragma unroll
    for (int p = 0; p < PP; ++p)
        s += b2f(L[((size_t)b*PP + p)*131072 + rem]);
    G[idx] = f2b(0.25f * s);
}

// ---------- s_attn: sigmoid( [xl, xg] . ws + bs ), one wave per row ----------
__global__ __launch_bounds__(256)
void sattn_kernel(const bf16* __restrict__ xl, const bf16* __restrict__ xg,
                  const float* __restrict__ wsv, const float* __restrict__ bs,
                  float* __restrict__ S)
{
    const int wave = threadIdx.x >> 6, lane = threadIdx.x & 63;
    const int row = blockIdx.x * 4 + wave;  // 0..8191
    const int b = row >> 10;
    const int n = row & 255;
    const bf16* xlr = xl + (size_t)row * RED;
    const bf16* xgr = xg + ((size_t)b*NN + n) * RED;
    float s = b2f(xlr[lane])    * wsv[lane]
            + b2f(xlr[lane+64]) * wsv[lane+64]
            + b2f(xgr[lane])    * wsv[RED+lane]
            + b2f(xgr[lane+64]) * wsv[RED+64+lane];
#pragma unroll
    for (int off = 32; off; off >>= 1) s += __shfl_xor(s, off);
    if (lane == 0) S[row] = 1.f / (1.f + __expf(-(s + bs[0])));
}

// ---------- fuse: x_new = x_attn_res + mlp_out * c_attn * s_attn ----------
__global__ void fuse_kernel(const float* __restrict__ xb, const float* __restrict__ m1,
                            const bf16* __restrict__ ca, const float* __restrict__ S,
                            float* __restrict__ xa)
{
    const int idx = blockIdx.x * 256 + threadIdx.x;  // < 4194304
    const int r = idx >> 9;
    const int d = idx & 511;
    const int b = r >> 10;
    const int n = r & 255;
    xa[idx] = xb[idx] + m1[idx] * b2f(ca[(((size_t)b << 8) + n)*DIM + d]) * S[r];
}

__global__ void copyf_kernel(const float* __restrict__ in, float* __restrict__ out)
{
    const int idx = blockIdx.x * 256 + threadIdx.x;
    out[idx] = in[idx];
}

// ---------- host launch ----------
extern "C" void kernel_launch(void* const* d_in, const int* in_sizes, int n_in,
                              void* d_out, int out_size, void* d_ws, size_t ws_size,
                              hipStream_t stream)
{
    const float* x_in  = (const float*)d_in[0];
    const float* ln1_g = (const float*)d_in[1];
    const float* ln1_b = (const float*)d_in[2];
    const float* w_qkv = (const float*)d_in[3];
    const float* w_o   = (const float*)d_in[4];
    const float* b_o   = (const float*)d_in[5];
    const float* ln2_g = (const float*)d_in[6];
    const float* ln2_b = (const float*)d_in[7];
    const float* w1    = (const float*)d_in[8];
    const float* b1    = (const float*)d_in[9];
    const float* w2    = (const float*)d_in[10];
    const float* b2    = (const float*)d_in[11];
    const float* bn_g  = (const float*)d_in[12];
    const float* bn_b  = (const float*)d_in[13];
    const float* wg    = (const float*)d_in[14];
    const float* bg    = (const float*)d_in[15];
    const float* wl    = (const float*)d_in[16];
    const float* bl    = (const float*)d_in[17];
    const float* wc    = (const float*)d_in[18];
    const float* bc    = (const float*)d_in[19];
    const float* wsw   = (const float*)d_in[20];
    const float* bsb   = (const float*)d_in[21];

    char* ws = (char*)d_ws;
    auto alloc = [&](size_t bytes) {
        char* p = ws;
        ws += (bytes + 255) & ~(size_t)255;
        return p;
    };
    float* XA = (float*)alloc(XELEMS * 4);            // residual stream (fp32)
    float* XB = (float*)alloc(XELEMS * 4);            // post-attention residual (fp32)
    float* M1 = (float*)alloc(XELEMS * 4);            // mlp2 out (fp32, "ori")
    bf16*  L  = (bf16*) alloc(XELEMS * 2);            // ln1 out / attn out / bn-ln out
    bf16*  Q  = (bf16*) alloc((size_t)ROWS * 3*DIM * 2); // qkv / ln2 out
    bf16*  H  = (bf16*) alloc((size_t)ROWS * MLPD * 2);  // mlp hidden
    bf16*  G  = (bf16*) alloc((size_t)BB*NN*DIM * 2);    // x_global (mean over p)
    bf16*  G2 = (bf16*) alloc((size_t)BB*NN*RED * 2);    // gelu(xg@wg+bg)
    bf16*  XL = (bf16*) alloc((size_t)ROWS*RED * 2);     // gelu(x@wl+bl)
    bf16*  CA = (bf16*) alloc((size_t)BB*NN*DIM * 2);    // c_attn
    float* S  = (float*)alloc((size_t)ROWS * 4);         // s_attn

    copyf_kernel<<<XELEMS/256, 256, 0, stream>>>(x_in, XA);

    for (int l = 0; l < DEPTH; ++l) {
        // ---- attention block ----
        ln_kernel<<<ROWS/4, 256, 0, stream>>>(XA, ln1_g + l*DIM, ln1_b + l*DIM, L, ROWS);
        gemm_kernel<false><<<dim3((3*DIM)/BN, ROWS/BM), 256, 0, stream>>>(
            L, w_qkv + (size_t)l*DIM*3*DIM, nullptr, nullptr, Q, ROWS, 3*DIM, DIM, 0);
        attn_kernel<<<BB*PP*HEADS, 256, 0, stream>>>(Q, L);
        gemm_kernel<true><<<dim3(DIM/BN, ROWS/BM), 256, 0, stream>>>(
            L, w_o + (size_t)l*DIM*DIM, b_o + l*DIM, XA, XB, ROWS, DIM, DIM, 0);

        // ---- MLP ----
        ln_kernel<<<ROWS/4, 256, 0, stream>>>(XB, ln2_g + l*DIM, ln2_b + l*DIM, Q, ROWS);
        gemm_kernel<false><<<dim3(MLPD/BN, ROWS/BM), 256, 0, stream>>>(
            Q, w1 + (size_t)l*DIM*MLPD, b1 + l*MLPD, nullptr, H, ROWS, MLPD, DIM, 1);
        gemm_kernel<true><<<dim3(DIM/BN, ROWS/BM), 256, 0, stream>>>(
            H, w2 + (size_t)l*MLPD*DIM, b2 + l*DIM, nullptr, M1, ROWS, DIM, MLPD, 0);

        // ---- BiAttn ----
        ln_kernel<<<ROWS/4, 256, 0, stream>>>(M1, bn_g + l*DIM, bn_b + l*DIM, L, ROWS);
        mean_kernel<<<(BB*NN*DIM)/256, 256, 0, stream>>>(L, G);
        gemm_kernel<false><<<dim3(RED/BN, (BB*NN)/BM), 256, 0, stream>>>(
            G, wg + (size_t)l*DIM*RED, bg + l*RED, nullptr, G2, BB*NN, RED, DIM, 1);
        gemm_kernel<false><<<dim3(RED/BN, ROWS/BM), 256, 0, stream>>>(
            L, wl + (size_t)l*DIM*RED, bl + l*RED, nullptr, XL, ROWS, RED, DIM, 1);
        gemm_kernel<false><<<dim3(DIM/BN, (BB*NN)/BM), 256, 0, stream>>>(
            G2, wc + (size_t)l*RED*DIM, bc + l*DIM, nullptr, CA, BB*NN, DIM, RED, 2);
        sattn_kernel<<<ROWS/4, 256, 0, stream>>>(XL, G2, wsw + (size_t)l*2*RED, bsb + l, S);
        fuse_kernel<<<XELEMS/256, 256, 0, stream>>>(XB, M1, CA, S, XA);
    }

    copyf_kernel<<<XELEMS/256, 256, 0, stream>>>(XA, (float*)d_out);
}

// Round 3
// 1884.991 us; speedup vs baseline: 2.6265x; 2.6265x over previous
//
#include <hip/hip_runtime.h>
#include <hip/hip_bf16.h>
#include <math.h>

typedef __hip_bfloat16 bf16;
typedef unsigned short u16;
typedef __bf16 bf16x8 __attribute__((ext_vector_type(8)));
typedef float f32x4 __attribute__((ext_vector_type(4)));

// ---------- helpers ----------
__device__ __forceinline__ float b2f(bf16 v) { return __bfloat162float(v); }
__device__ __forceinline__ bf16 f2b(float v) { return __float2bfloat16(v); }
__device__ __forceinline__ float bits2f(unsigned int u) {
    union { unsigned int i; float f; } w; w.i = u << 16; return w.f;
}
__device__ __forceinline__ u16 f2bits(float v) {
    union { bf16 h; u16 u; } w; w.h = __float2bfloat16(v); return w.u;
}
__device__ __forceinline__ void async16(void* lds, const void* g) {
    __builtin_amdgcn_global_load_lds(
        (const __attribute__((address_space(1))) unsigned int*)g,
        (__attribute__((address_space(3))) unsigned int*)lds, 16, 0, 0);
}

#define DEPTH 4
#define HEADS 8
#define DHEAD 64
#define DIM 512
#define MLPD 2048
#define RED 128
#define BB 8
#define PP 4
#define NN 256
#define ROWS (BB*PP*NN)          // 8192 tokens
#define XELEMS ((size_t)ROWS*DIM) // 4194304

// ---------- weight transpose+cast: W fp32 [K][N] -> WT bf16 [N][K] ----------
__global__ __launch_bounds__(256)
void wtrans_kernel(const float* __restrict__ W, u16* __restrict__ WT, int K, int N)
{
    __shared__ float T[32][33];
    const int tx = threadIdx.x & 31, ty = threadIdx.x >> 5; // ty 0..7
    const int n0 = blockIdx.x * 32, k0 = blockIdx.y * 32;
#pragma unroll
    for (int r = 0; r < 4; ++r)
        T[ty + r*8][tx] = W[(size_t)(k0 + ty + r*8) * N + n0 + tx];
    __syncthreads();
#pragma unroll
    for (int r = 0; r < 4; ++r)
        WT[(size_t)(n0 + ty + r*8) * K + k0 + tx] = f2bits(T[tx][ty + r*8]);
}

// ---------- MFMA GEMM: C = act(A @ WT^T + bias) [+res]
// A bf16 [M,K] row-major, WT bf16 [N,K] row-major. 128x128 tile, BK=32.
// 4 waves, each 64x64 (4x4 accs of 16x16x32).
__global__ __launch_bounds__(256)
void gemm_mfma(const u16* __restrict__ A, const u16* __restrict__ WT,
               const float* __restrict__ bias, const float* __restrict__ res,
               void* __restrict__ Cv, int M, int N, int K, int act, int outf32)
{
    __shared__ u16 As[128*32];
    __shared__ u16 Bs[128*32];
    const int tid  = threadIdx.x;
    const int wave = tid >> 6;
    const int lane = tid & 63;
    const int bm = blockIdx.y * 128;
    const int bn = blockIdx.x * 128;
    const int m0 = (wave >> 1) * 64;
    const int n0 = (wave & 1) * 64;
    const int lr = lane & 15;      // frag row/col within 16
    const int q  = lane >> 4;      // quad
    const int p  = q ^ ((lr >> 1) & 3);  // swizzled col-group for frag reads

    // staging: chunk c = wave*2+t covers 16 rows; lane -> (row, swizzled col-group)
    const int srow = lane >> 2;                          // 0..15
    const int sg   = ((lane & 3) ^ ((lane >> 3) & 3)) * 8; // swizzled k-offset (elems)

    f32x4 acc[4][4] = {};

    for (int k0 = 0; k0 < K; k0 += 32) {
        __syncthreads();
#pragma unroll
        for (int t = 0; t < 2; ++t) {
            const int c = wave*2 + t;
            const int row = c*16 + srow;
            async16(&As[c*512], A  + (size_t)(bm + row) * K + k0 + sg);
            async16(&Bs[c*512], WT + (size_t)(bn + row) * K + k0 + sg);
        }
        __syncthreads();
        bf16x8 af[4], bv[4];
#pragma unroll
        for (int i = 0; i < 4; ++i)
            af[i] = *(const bf16x8*)(As + (m0 + i*16 + lr)*32 + p*8);
#pragma unroll
        for (int j = 0; j < 4; ++j)
            bv[j] = *(const bf16x8*)(Bs + (n0 + j*16 + lr)*32 + p*8);
#pragma unroll
        for (int i = 0; i < 4; ++i)
#pragma unroll
            for (int j = 0; j < 4; ++j)
                acc[i][j] = __builtin_amdgcn_mfma_f32_16x16x32_bf16(
                    af[i], bv[j], acc[i][j], 0, 0, 0);
    }

    // epilogue: C/D layout col=lane&15, row=quad*4+reg
#pragma unroll
    for (int i = 0; i < 4; ++i) {
        const int rowb = bm + m0 + i*16 + q*4;
#pragma unroll
        for (int j = 0; j < 4; ++j) {
            const int col = bn + n0 + j*16 + lr;
            const float bvs = bias ? bias[col] : 0.f;
#pragma unroll
            for (int r = 0; r < 4; ++r) {
                float v = acc[i][j][r] + bvs;
                if (act == 1) v = 0.5f * v * (1.0f + erff(v * 0.70710678118f));
                else if (act == 2) v = 1.0f / (1.0f + __expf(-v));
                const size_t idx = (size_t)(rowb + r) * N + col;
                if (res) v += res[idx];
                if (outf32) ((float*)Cv)[idx] = v;
                else        ((u16*)Cv)[idx] = f2bits(v);
            }
        }
    }
}

// ---------- LayerNorm over DIM=512, input fp32, params fp32, output bf16 ----------
__global__ __launch_bounds__(256)
void ln_kernel(const float* __restrict__ x, const float* __restrict__ g,
               const float* __restrict__ b, bf16* __restrict__ y, int rows)
{
    const int wave = threadIdx.x >> 6;
    const int lane = threadIdx.x & 63;
    const int row = blockIdx.x * 4 + wave;
    if (row >= rows) return;
    const float* xr = x + (size_t)row * DIM;
    float v[8]; float s = 0.f, s2 = 0.f;
#pragma unroll
    for (int i = 0; i < 8; ++i) {
        v[i] = xr[lane + 64*i];
        s += v[i]; s2 += v[i]*v[i];
    }
#pragma unroll
    for (int off = 32; off; off >>= 1) { s += __shfl_xor(s, off); s2 += __shfl_xor(s2, off); }
    const float mean = s * (1.f/512.f);
    const float var  = s2 * (1.f/512.f) - mean*mean;
    const float rstd = rsqrtf(var + 1e-5f);
    bf16* yr = y + (size_t)row * DIM;
#pragma unroll
    for (int i = 0; i < 8; ++i) {
        const int d = lane + 64*i;
        yr[d] = f2b((v[i]-mean)*rstd*g[d] + b[d]);
    }
}

// ---------- attention: one block per (b,p,h); thread = query row; online softmax ----------
__global__ __launch_bounds__(256)
void attn_kernel(const bf16* __restrict__ qkv, bf16* __restrict__ out)
{
    __shared__ bf16 Ks[NN][DHEAD];
    __shared__ bf16 Vs[NN][DHEAD];
    const int bp = blockIdx.x >> 3;   // 0..31
    const int h  = blockIdx.x & 7;
    const bf16* base = qkv + (size_t)bp * NN * (3*DIM);
    const int qo = h * DHEAD;
    const int ko = DIM + h * DHEAD;
    const int vo = 2*DIM + h * DHEAD;

    for (int idx = threadIdx.x; idx < NN*DHEAD; idx += 256) {
        const int j = idx >> 6, d = idx & 63;
        Ks[j][d] = base[(size_t)j*(3*DIM) + ko + d];
        Vs[j][d] = base[(size_t)j*(3*DIM) + vo + d];
    }
    __syncthreads();

    const int i = threadIdx.x;
    float q[DHEAD];
#pragma unroll
    for (int d = 0; d < DHEAD; ++d)
        q[d] = b2f(base[(size_t)i*(3*DIM) + qo + d]) * 0.125f; // fold 1/sqrt(64)

    float m = -1e30f, l = 0.f;
    float o[DHEAD] = {};
    for (int j = 0; j < NN; ++j) {
        const unsigned int* Kj = (const unsigned int*)(&Ks[j][0]);
        float s = 0.f;
#pragma unroll
        for (int dd = 0; dd < 32; ++dd) {
            unsigned int w = Kj[dd];
            s = fmaf(q[2*dd],   bits2f(w & 0xffffu), s);
            s = fmaf(q[2*dd+1], bits2f(w >> 16),     s);
        }
        if (s > m) {
            const float alpha = __expf(m - s);
            l *= alpha;
#pragma unroll
            for (int d = 0; d < DHEAD; ++d) o[d] *= alpha;
            m = s;
        }
        const float pr = __expf(s - m);
        l += pr;
        const unsigned int* Vj = (const unsigned int*)(&Vs[j][0]);
#pragma unroll
        for (int dd = 0; dd < 32; ++dd) {
            unsigned int w = Vj[dd];
            o[2*dd]   = fmaf(pr, bits2f(w & 0xffffu), o[2*dd]);
            o[2*dd+1] = fmaf(pr, bits2f(w >> 16),     o[2*dd+1]);
        }
    }
    const float inv = 1.0f / l;
    bf16* orow = out + ((size_t)bp*NN + i) * DIM + h*DHEAD;
#pragma unroll
    for (int d = 0; d < DHEAD; ++d) orow[d] = f2b(o[d] * inv);
}

// ---------- mean over P of LN'd x: [b,p,n,d] -> [b,n,d] ----------
__global__ void mean_kernel(const bf16* __restrict__ L, bf16* __restrict__ G)
{
    const int idx = blockIdx.x * 256 + threadIdx.x;  // < 8*256*512
    const int b = idx >> 17;
    const int rem = idx & 131071;
    float s = 0.f;
#pragma unroll
    for (int p = 0; p < PP; ++p)
        s += b2f(L[((size_t)b*PP + p)*131072 + rem]);
    G[idx] = f2b(0.25f * s);
}

// ---------- s_attn: sigmoid( [xl, xg] . ws + bs ), one wave per row ----------
__global__ __launch_bounds__(256)
void sattn_kernel(const bf16* __restrict__ xl, const bf16* __restrict__ xg,
                  const float* __restrict__ wsv, const float* __restrict__ bs,
                  float* __restrict__ S)
{
    const int wave = threadIdx.x >> 6, lane = threadIdx.x & 63;
    const int row = blockIdx.x * 4 + wave;  // 0..8191
    const int b = row >> 10;
    const int n = row & 255;
    const bf16* xlr = xl + (size_t)row * RED;
    const bf16* xgr = xg + ((size_t)b*NN + n) * RED;
    float s = b2f(xlr[lane])    * wsv[lane]
            + b2f(xlr[lane+64]) * wsv[lane+64]
            + b2f(xgr[lane])    * wsv[RED+lane]
            + b2f(xgr[lane+64]) * wsv[RED+64+lane];
#pragma unroll
    for (int off = 32; off; off >>= 1) s += __shfl_xor(s, off);
    if (lane == 0) S[row] = 1.f / (1.f + __expf(-(s + bs[0])));
}

// ---------- fuse: x_new = x_attn_res + mlp_out * c_attn * s_attn ----------
__global__ void fuse_kernel(const float* __restrict__ xb, const float* __restrict__ m1,
                            const bf16* __restrict__ ca, const float* __restrict__ S,
                            float* __restrict__ xa)
{
    const int idx = blockIdx.x * 256 + threadIdx.x;  // < 4194304
    const int r = idx >> 9;
    const int d = idx & 511;
    const int b = r >> 10;
    const int n = r & 255;
    xa[idx] = xb[idx] + m1[idx] * b2f(ca[(((size_t)b << 8) + n)*DIM + d]) * S[r];
}

__global__ void copyf_kernel(const float* __restrict__ in, float* __restrict__ out)
{
    const int idx = blockIdx.x * 256 + threadIdx.x;
    out[idx] = in[idx];
}

// ---------- host launch ----------
extern "C" void kernel_launch(void* const* d_in, const int* in_sizes, int n_in,
                              void* d_out, int out_size, void* d_ws, size_t ws_size,
                              hipStream_t stream)
{
    const float* x_in  = (const float*)d_in[0];
    const float* ln1_g = (const float*)d_in[1];
    const float* ln1_b = (const float*)d_in[2];
    const float* w_qkv = (const float*)d_in[3];
    const float* w_o   = (const float*)d_in[4];
    const float* b_o   = (const float*)d_in[5];
    const float* ln2_g = (const float*)d_in[6];
    const float* ln2_b = (const float*)d_in[7];
    const float* w1    = (const float*)d_in[8];
    const float* b1    = (const float*)d_in[9];
    const float* w2    = (const float*)d_in[10];
    const float* b2    = (const float*)d_in[11];
    const float* bn_g  = (const float*)d_in[12];
    const float* bn_b  = (const float*)d_in[13];
    const float* wg    = (const float*)d_in[14];
    const float* bg    = (const float*)d_in[15];
    const float* wl    = (const float*)d_in[16];
    const float* bl    = (const float*)d_in[17];
    const float* wc    = (const float*)d_in[18];
    const float* bc    = (const float*)d_in[19];
    const float* wsw   = (const float*)d_in[20];
    const float* bsb   = (const float*)d_in[21];

    char* ws = (char*)d_ws;
    auto alloc = [&](size_t bytes) {
        char* p = ws;
        ws += (bytes + 255) & ~(size_t)255;
        return p;
    };
    float* XA = (float*)alloc(XELEMS * 4);            // residual stream (fp32)
    float* XB = (float*)alloc(XELEMS * 4);            // post-attention residual (fp32)
    float* M1 = (float*)alloc(XELEMS * 4);            // mlp2 out (fp32, "ori")
    u16*   L  = (u16*)  alloc(XELEMS * 2);            // ln1 out / attn out / bn-ln out
    u16*   Q  = (u16*)  alloc((size_t)ROWS * 3*DIM * 2); // qkv / ln2 out
    u16*   H  = (u16*)  alloc((size_t)ROWS * MLPD * 2);  // mlp hidden
    u16*   G  = (u16*)  alloc((size_t)BB*NN*DIM * 2);    // x_global (mean over p)
    u16*   G2 = (u16*)  alloc((size_t)BB*NN*RED * 2);    // gelu(xg@wg+bg)
    u16*   XL = (u16*)  alloc((size_t)ROWS*RED * 2);     // gelu(x@wl+bl)
    u16*   CA = (u16*)  alloc((size_t)BB*NN*DIM * 2);    // c_attn
    float* S  = (float*)alloc((size_t)ROWS * 4);         // s_attn
    // per-layer transposed bf16 weights (reused each layer)
    u16* WTqkv = (u16*)alloc((size_t)DIM*3*DIM * 2);     // [1536][512]
    u16* WTo   = (u16*)alloc((size_t)DIM*DIM * 2);       // [512][512]
    u16* WT1   = (u16*)alloc((size_t)DIM*MLPD * 2);      // [2048][512]
    u16* WT2   = (u16*)alloc((size_t)MLPD*DIM * 2);      // [512][2048]
    u16* WTl   = (u16*)alloc((size_t)DIM*RED * 2);       // [128][512]
    u16* WTg   = (u16*)alloc((size_t)DIM*RED * 2);       // [128][512]
    u16* WTc   = (u16*)alloc((size_t)RED*DIM * 2);       // [512][128]

    copyf_kernel<<<XELEMS/256, 256, 0, stream>>>(x_in, XA);

    for (int l = 0; l < DEPTH; ++l) {
        // ---- weight prep (transpose + bf16 cast) ----
        wtrans_kernel<<<dim3(48,16), 256, 0, stream>>>(w_qkv + (size_t)l*DIM*3*DIM, WTqkv, DIM, 3*DIM);
        wtrans_kernel<<<dim3(16,16), 256, 0, stream>>>(w_o   + (size_t)l*DIM*DIM,   WTo,   DIM, DIM);
        wtrans_kernel<<<dim3(64,16), 256, 0, stream>>>(w1    + (size_t)l*DIM*MLPD,  WT1,   DIM, MLPD);
        wtrans_kernel<<<dim3(16,64), 256, 0, stream>>>(w2    + (size_t)l*MLPD*DIM,  WT2,   MLPD, DIM);
        wtrans_kernel<<<dim3(4,16),  256, 0, stream>>>(wl    + (size_t)l*DIM*RED,   WTl,   DIM, RED);
        wtrans_kernel<<<dim3(4,16),  256, 0, stream>>>(wg    + (size_t)l*DIM*RED,   WTg,   DIM, RED);
        wtrans_kernel<<<dim3(16,4),  256, 0, stream>>>(wc    + (size_t)l*RED*DIM,   WTc,   RED, DIM);

        // ---- attention block ----
        ln_kernel<<<ROWS/4, 256, 0, stream>>>(XA, ln1_g + l*DIM, ln1_b + l*DIM, (bf16*)L, ROWS);
        gemm_mfma<<<dim3(12,64), 256, 0, stream>>>(L, WTqkv, nullptr, nullptr, Q,
                                                   ROWS, 3*DIM, DIM, 0, 0);
        attn_kernel<<<BB*PP*HEADS, 256, 0, stream>>>((const bf16*)Q, (bf16*)L);
        gemm_mfma<<<dim3(4,64), 256, 0, stream>>>(L, WTo, b_o + l*DIM, XA, XB,
                                                  ROWS, DIM, DIM, 0, 1);

        // ---- MLP ----
        ln_kernel<<<ROWS/4, 256, 0, stream>>>(XB, ln2_g + l*DIM, ln2_b + l*DIM, (bf16*)Q, ROWS);
        gemm_mfma<<<dim3(16,64), 256, 0, stream>>>(Q, WT1, b1 + l*MLPD, nullptr, H,
                                                   ROWS, MLPD, DIM, 1, 0);
        gemm_mfma<<<dim3(4,64), 256, 0, stream>>>(H, WT2, b2 + l*DIM, nullptr, M1,
                                                  ROWS, DIM, MLPD, 0, 1);

        // ---- BiAttn ----
        ln_kernel<<<ROWS/4, 256, 0, stream>>>(M1, bn_g + l*DIM, bn_b + l*DIM, (bf16*)L, ROWS);
        mean_kernel<<<(BB*NN*DIM)/256, 256, 0, stream>>>((const bf16*)L, (bf16*)G);
        gemm_mfma<<<dim3(1,16), 256, 0, stream>>>(G, WTg, bg + l*RED, nullptr, G2,
                                                  BB*NN, RED, DIM, 1, 0);
        gemm_mfma<<<dim3(1,64), 256, 0, stream>>>(L, WTl, bl + l*RED, nullptr, XL,
                                                  ROWS, RED, DIM, 1, 0);
        gemm_mfma<<<dim3(4,16), 256, 0, stream>>>(G2, WTc, bc + l*DIM, nullptr, CA,
                                                  BB*NN, DIM, RED, 2, 0);
        sattn_kernel<<<ROWS/4, 256, 0, stream>>>((const bf16*)XL, (const bf16*)G2,
                                                 wsw + (size_t)l*2*RED, bsb + l, S);
        fuse_kernel<<<XELEMS/256, 256, 0, stream>>>(XB, M1, (const bf16*)CA, S, XA);
    }

    copyf_kernel<<<XELEMS/256, 256, 0, stream>>>(XA, (float*)d_out);
}

// Round 4
// 1376.447 us; speedup vs baseline: 3.5969x; 1.3695x over previous
//
#include <hip/hip_runtime.h>
#include <hip/hip_bf16.h>
#include <math.h>

typedef __hip_bfloat16 bf16;
typedef unsigned short u16;
typedef __bf16 bf16x8 __attribute__((ext_vector_type(8)));
typedef float f32x4 __attribute__((ext_vector_type(4)));

// ---------- helpers ----------
__device__ __forceinline__ float b2f(bf16 v) { return __bfloat162float(v); }
__device__ __forceinline__ bf16 f2b(float v) { return __float2bfloat16(v); }
__device__ __forceinline__ float bits2f(unsigned int u) {
    union { unsigned int i; float f; } w; w.i = u << 16; return w.f;
}
__device__ __forceinline__ u16 f2bits(float v) {
    union { bf16 h; u16 u; } w; w.h = __float2bfloat16(v); return w.u;
}
__device__ __forceinline__ void async16(void* lds, const void* g) {
    __builtin_amdgcn_global_load_lds(
        (const __attribute__((address_space(1))) unsigned int*)g,
        (__attribute__((address_space(3))) unsigned int*)lds, 16, 0, 0);
}

#define DEPTH 4
#define HEADS 8
#define DHEAD 64
#define DIM 512
#define MLPD 2048
#define RED 128
#define BB 8
#define PP 4
#define NN 256
#define ROWS (BB*PP*NN)          // 8192 tokens
#define XELEMS ((size_t)ROWS*DIM) // 4194304

// ---------- weight transpose+cast: W fp32 [K][N] -> WT bf16 [N][K] ----------
__global__ __launch_bounds__(256)
void wtrans_kernel(const float* __restrict__ W, u16* __restrict__ WT, int K, int N)
{
    __shared__ float T[32][33];
    const int tx = threadIdx.x & 31, ty = threadIdx.x >> 5; // ty 0..7
    const int n0 = blockIdx.x * 32, k0 = blockIdx.y * 32;
#pragma unroll
    for (int r = 0; r < 4; ++r)
        T[ty + r*8][tx] = W[(size_t)(k0 + ty + r*8) * N + n0 + tx];
    __syncthreads();
#pragma unroll
    for (int r = 0; r < 4; ++r)
        WT[(size_t)(n0 + ty + r*8) * K + k0 + tx] = f2bits(T[tx][ty + r*8]);
}

// ---------- MFMA GEMM: C = act(A @ WT^T + bias) [+res]
// A bf16 [M,K] row-major, WT bf16 [N,K] row-major. 128x128 tile, BK=32.
__global__ __launch_bounds__(256)
void gemm_mfma(const u16* __restrict__ A, const u16* __restrict__ WT,
               const float* __restrict__ bias, const float* __restrict__ res,
               void* __restrict__ Cv, int M, int N, int K, int act, int outf32)
{
    __shared__ u16 As[128*32];
    __shared__ u16 Bs[128*32];
    const int tid  = threadIdx.x;
    const int wave = tid >> 6;
    const int lane = tid & 63;
    const int bm = blockIdx.y * 128;
    const int bn = blockIdx.x * 128;
    const int m0 = (wave >> 1) * 64;
    const int n0 = (wave & 1) * 64;
    const int lr = lane & 15;      // frag row/col within 16
    const int q  = lane >> 4;      // quad
    const int p  = q ^ ((lr >> 1) & 3);  // swizzled col-group for frag reads

    const int srow = lane >> 2;                          // 0..15
    const int sg   = ((lane & 3) ^ ((lane >> 3) & 3)) * 8; // swizzled k-offset (elems)

    f32x4 acc[4][4] = {};

    for (int k0 = 0; k0 < K; k0 += 32) {
        __syncthreads();
#pragma unroll
        for (int t = 0; t < 2; ++t) {
            const int c = wave*2 + t;
            const int row = c*16 + srow;
            async16(&As[c*512], A  + (size_t)(bm + row) * K + k0 + sg);
            async16(&Bs[c*512], WT + (size_t)(bn + row) * K + k0 + sg);
        }
        __syncthreads();
        bf16x8 af[4], bv[4];
#pragma unroll
        for (int i = 0; i < 4; ++i)
            af[i] = *(const bf16x8*)(As + (m0 + i*16 + lr)*32 + p*8);
#pragma unroll
        for (int j = 0; j < 4; ++j)
            bv[j] = *(const bf16x8*)(Bs + (n0 + j*16 + lr)*32 + p*8);
#pragma unroll
        for (int i = 0; i < 4; ++i)
#pragma unroll
            for (int j = 0; j < 4; ++j)
                acc[i][j] = __builtin_amdgcn_mfma_f32_16x16x32_bf16(
                    af[i], bv[j], acc[i][j], 0, 0, 0);
    }

#pragma unroll
    for (int i = 0; i < 4; ++i) {
        const int rowb = bm + m0 + i*16 + q*4;
#pragma unroll
        for (int j = 0; j < 4; ++j) {
            const int col = bn + n0 + j*16 + lr;
            const float bvs = bias ? bias[col] : 0.f;
#pragma unroll
            for (int r = 0; r < 4; ++r) {
                float v = acc[i][j][r] + bvs;
                if (act == 1) v = 0.5f * v * (1.0f + erff(v * 0.70710678118f));
                else if (act == 2) v = 1.0f / (1.0f + __expf(-v));
                const size_t idx = (size_t)(rowb + r) * N + col;
                if (res) v += res[idx];
                if (outf32) ((float*)Cv)[idx] = v;
                else        ((u16*)Cv)[idx] = f2bits(v);
            }
        }
    }
}

// ---------- MFMA flash attention: one block per (b,p,h), wave = 64 query rows ----------
__global__ __launch_bounds__(256)
void attn_mfma(const u16* __restrict__ qkv, u16* __restrict__ out)
{
    __shared__ u16 Kt[64*72];        // K-tile [key][d], padded stride 72
    __shared__ u16 Vt[64*72];        // V-tile transposed [d][key], stride 72
    __shared__ u16 Pw[4][64*72];     // per-wave P tile [qrow][key], stride 72
    const int tid = threadIdx.x;
    const int wave = tid >> 6, lane = tid & 63;
    const int lr = lane & 15, quad = lane >> 4;
    const int bp = blockIdx.x >> 3, h = blockIdx.x & 7;
    const u16* base = qkv + (size_t)bp * NN * (3*DIM);
    const int qo = h*DHEAD, ko = DIM + h*DHEAD, vo = 2*DIM + h*DHEAD;
    const int m0 = wave * 64;

    // Q fragments (A-layout): rows m0+i*16+lr, k = kb*32 + quad*8
    bf16x8 qf[4][2];
#pragma unroll
    for (int i = 0; i < 4; ++i)
#pragma unroll
        for (int kb = 0; kb < 2; ++kb)
            qf[i][kb] = *(const bf16x8*)(base + (size_t)(m0 + i*16 + lr)*(3*DIM)
                                         + qo + kb*32 + quad*8);

    f32x4 o[4][4] = {};
    float mrow[4][4], lrow[4][4];
#pragma unroll
    for (int i = 0; i < 4; ++i)
#pragma unroll
        for (int r = 0; r < 4; ++r) { mrow[i][r] = -1e30f; lrow[i][r] = 0.f; }

    const int sr = tid >> 3, sc = tid & 7;   // staging: row, chunk

    for (int t = 0; t < 4; ++t) {
        __syncthreads();
        // stage K tile and transposed V tile
#pragma unroll
        for (int half = 0; half < 2; ++half) {
            const int key = half*32 + sr;
            const u16* krow = base + (size_t)(t*64 + key)*(3*DIM);
            uint4 kv = *(const uint4*)(krow + ko + sc*8);
            *(uint4*)(Kt + key*72 + sc*8) = kv;
            uint4 vv = *(const uint4*)(krow + vo + sc*8);
            const int d0 = sc*8;
            Vt[(d0+0)*72 + key] = (u16)(vv.x & 0xffffu);
            Vt[(d0+1)*72 + key] = (u16)(vv.x >> 16);
            Vt[(d0+2)*72 + key] = (u16)(vv.y & 0xffffu);
            Vt[(d0+3)*72 + key] = (u16)(vv.y >> 16);
            Vt[(d0+4)*72 + key] = (u16)(vv.z & 0xffffu);
            Vt[(d0+5)*72 + key] = (u16)(vv.z >> 16);
            Vt[(d0+6)*72 + key] = (u16)(vv.w & 0xffffu);
            Vt[(d0+7)*72 + key] = (u16)(vv.w >> 16);
        }
        __syncthreads();

        // S = Q K^T for this tile
        f32x4 s[4][4] = {};
        bf16x8 kf[4][2];
#pragma unroll
        for (int j = 0; j < 4; ++j)
#pragma unroll
            for (int kb = 0; kb < 2; ++kb)
                kf[j][kb] = *(const bf16x8*)(Kt + (j*16 + lr)*72 + kb*32 + quad*8);
#pragma unroll
        for (int i = 0; i < 4; ++i)
#pragma unroll
            for (int j = 0; j < 4; ++j)
#pragma unroll
                for (int kb = 0; kb < 2; ++kb)
                    s[i][j] = __builtin_amdgcn_mfma_f32_16x16x32_bf16(
                        qf[i][kb], kf[j][kb], s[i][j], 0, 0, 0);

        // online softmax (scale 1/8 folded here)
        float alpha[4][4];
#pragma unroll
        for (int i = 0; i < 4; ++i)
#pragma unroll
            for (int r = 0; r < 4; ++r) {
#pragma unroll
                for (int j = 0; j < 4; ++j) s[i][j][r] *= 0.125f;
                float mt = fmaxf(fmaxf(s[i][0][r], s[i][1][r]),
                                 fmaxf(s[i][2][r], s[i][3][r]));
#pragma unroll
                for (int off = 1; off <= 8; off <<= 1) mt = fmaxf(mt, __shfl_xor(mt, off));
                const float mn = fmaxf(mrow[i][r], mt);
                alpha[i][r] = __expf(mrow[i][r] - mn);
                mrow[i][r] = mn;
                float ssum = 0.f;
#pragma unroll
                for (int j = 0; j < 4; ++j) {
                    const float p = __expf(s[i][j][r] - mn);
                    s[i][j][r] = p; ssum += p;
                }
#pragma unroll
                for (int off = 1; off <= 8; off <<= 1) ssum += __shfl_xor(ssum, off);
                lrow[i][r] = lrow[i][r]*alpha[i][r] + ssum;
            }

        // write P (C-layout) to per-wave LDS tile
#pragma unroll
        for (int i = 0; i < 4; ++i)
#pragma unroll
            for (int j = 0; j < 4; ++j)
#pragma unroll
                for (int r = 0; r < 4; ++r)
                    Pw[wave][(i*16 + quad*4 + r)*72 + j*16 + lr] = f2bits(s[i][j][r]);
        __syncthreads();

        // rescale O, then PV accumulate
#pragma unroll
        for (int i = 0; i < 4; ++i)
#pragma unroll
            for (int jd = 0; jd < 4; ++jd)
#pragma unroll
                for (int r = 0; r < 4; ++r) o[i][jd][r] *= alpha[i][r];

        bf16x8 af[4][2], bv[4][2];
#pragma unroll
        for (int i = 0; i < 4; ++i)
#pragma unroll
            for (int kb = 0; kb < 2; ++kb)
                af[i][kb] = *(const bf16x8*)(Pw[wave] + (i*16 + lr)*72 + kb*32 + quad*8);
#pragma unroll
        for (int jd = 0; jd < 4; ++jd)
#pragma unroll
            for (int kb = 0; kb < 2; ++kb)
                bv[jd][kb] = *(const bf16x8*)(Vt + (jd*16 + lr)*72 + kb*32 + quad*8);
#pragma unroll
        for (int i = 0; i < 4; ++i)
#pragma unroll
            for (int jd = 0; jd < 4; ++jd)
#pragma unroll
                for (int kb = 0; kb < 2; ++kb)
                    o[i][jd] = __builtin_amdgcn_mfma_f32_16x16x32_bf16(
                        af[i][kb], bv[jd][kb], o[i][jd], 0, 0, 0);
    }

    // epilogue: normalize and store
#pragma unroll
    for (int i = 0; i < 4; ++i)
#pragma unroll
        for (int r = 0; r < 4; ++r) {
            const float inv = 1.0f / lrow[i][r];
            const size_t rowg = (size_t)bp*NN + m0 + i*16 + quad*4 + r;
#pragma unroll
            for (int jd = 0; jd < 4; ++jd)
                out[rowg*DIM + h*DHEAD + jd*16 + lr] = f2bits(o[i][jd][r] * inv);
        }
}

// ---------- LayerNorm over DIM=512, input fp32, params fp32, output bf16 ----------
__global__ __launch_bounds__(256)
void ln_kernel(const float* __restrict__ x, const float* __restrict__ g,
               const float* __restrict__ b, bf16* __restrict__ y, int rows)
{
    const int wave = threadIdx.x >> 6;
    const int lane = threadIdx.x & 63;
    const int row = blockIdx.x * 4 + wave;
    if (row >= rows) return;
    const float* xr = x + (size_t)row * DIM;
    float v[8]; float s = 0.f, s2 = 0.f;
#pragma unroll
    for (int i = 0; i < 8; ++i) {
        v[i] = xr[lane + 64*i];
        s += v[i]; s2 += v[i]*v[i];
    }
#pragma unroll
    for (int off = 32; off; off >>= 1) { s += __shfl_xor(s, off); s2 += __shfl_xor(s2, off); }
    const float mean = s * (1.f/512.f);
    const float var  = s2 * (1.f/512.f) - mean*mean;
    const float rstd = rsqrtf(var + 1e-5f);
    bf16* yr = y + (size_t)row * DIM;
#pragma unroll
    for (int i = 0; i < 8; ++i) {
        const int d = lane + 64*i;
        yr[d] = f2b((v[i]-mean)*rstd*g[d] + b[d]);
    }
}

// ---------- mean over P of LN'd x: [b,p,n,d] -> [b,n,d] ----------
__global__ void mean_kernel(const bf16* __restrict__ L, bf16* __restrict__ G)
{
    const int idx = blockIdx.x * 256 + threadIdx.x;  // < 8*256*512
    const int b = idx >> 17;
    const int rem = idx & 131071;
    float s = 0.f;
#pragma unroll
    for (int p = 0; p < PP; ++p)
        s += b2f(L[((size_t)b*PP + p)*131072 + rem]);
    G[idx] = f2b(0.25f * s);
}

// ---------- s_attn: sigmoid( [xl, xg] . ws + bs ), one wave per row ----------
__global__ __launch_bounds__(256)
void sattn_kernel(const bf16* __restrict__ xl, const bf16* __restrict__ xg,
                  const float* __restrict__ wsv, const float* __restrict__ bs,
                  float* __restrict__ S)
{
    const int wave = threadIdx.x >> 6, lane = threadIdx.x & 63;
    const int row = blockIdx.x * 4 + wave;  // 0..8191
    const int b = row >> 10;
    const int n = row & 255;
    const bf16* xlr = xl + (size_t)row * RED;
    const bf16* xgr = xg + ((size_t)b*NN + n) * RED;
    float s = b2f(xlr[lane])    * wsv[lane]
            + b2f(xlr[lane+64]) * wsv[lane+64]
            + b2f(xgr[lane])    * wsv[RED+lane]
            + b2f(xgr[lane+64]) * wsv[RED+64+lane];
#pragma unroll
    for (int off = 32; off; off >>= 1) s += __shfl_xor(s, off);
    if (lane == 0) S[row] = 1.f / (1.f + __expf(-(s + bs[0])));
}

// ---------- fuse: x_new = x_attn_res + mlp_out * c_attn * s_attn ----------
__global__ void fuse_kernel(const float* __restrict__ xb, const float* __restrict__ m1,
                            const bf16* __restrict__ ca, const float* __restrict__ S,
                            float* __restrict__ xa)
{
    const int idx = blockIdx.x * 256 + threadIdx.x;  // < 4194304
    const int r = idx >> 9;
    const int d = idx & 511;
    const int b = r >> 10;
    const int n = r & 255;
    xa[idx] = xb[idx] + m1[idx] * b2f(ca[(((size_t)b << 8) + n)*DIM + d]) * S[r];
}

__global__ void copyf_kernel(const float* __restrict__ in, float* __restrict__ out)
{
    const int idx = blockIdx.x * 256 + threadIdx.x;
    out[idx] = in[idx];
}

// ---------- host launch ----------
extern "C" void kernel_launch(void* const* d_in, const int* in_sizes, int n_in,
                              void* d_out, int out_size, void* d_ws, size_t ws_size,
                              hipStream_t stream)
{
    const float* x_in  = (const float*)d_in[0];
    const float* ln1_g = (const float*)d_in[1];
    const float* ln1_b = (const float*)d_in[2];
    const float* w_qkv = (const float*)d_in[3];
    const float* w_o   = (const float*)d_in[4];
    const float* b_o   = (const float*)d_in[5];
    const float* ln2_g = (const float*)d_in[6];
    const float* ln2_b = (const float*)d_in[7];
    const float* w1    = (const float*)d_in[8];
    const float* b1    = (const float*)d_in[9];
    const float* w2    = (const float*)d_in[10];
    const float* b2    = (const float*)d_in[11];
    const float* bn_g  = (const float*)d_in[12];
    const float* bn_b  = (const float*)d_in[13];
    const float* wg    = (const float*)d_in[14];
    const float* bg    = (const float*)d_in[15];
    const float* wl    = (const float*)d_in[16];
    const float* bl    = (const float*)d_in[17];
    const float* wc    = (const float*)d_in[18];
    const float* bc    = (const float*)d_in[19];
    const float* wsw   = (const float*)d_in[20];
    const float* bsb   = (const float*)d_in[21];

    char* ws = (char*)d_ws;
    auto alloc = [&](size_t bytes) {
        char* p = ws;
        ws += (bytes + 255) & ~(size_t)255;
        return p;
    };
    float* XA = (float*)alloc(XELEMS * 4);
    float* XB = (float*)alloc(XELEMS * 4);
    float* M1 = (float*)alloc(XELEMS * 4);
    u16*   L  = (u16*)  alloc(XELEMS * 2);
    u16*   Q  = (u16*)  alloc((size_t)ROWS * 3*DIM * 2);
    u16*   H  = (u16*)  alloc((size_t)ROWS * MLPD * 2);
    u16*   G  = (u16*)  alloc((size_t)BB*NN*DIM * 2);
    u16*   G2 = (u16*)  alloc((size_t)BB*NN*RED * 2);
    u16*   XL = (u16*)  alloc((size_t)ROWS*RED * 2);
    u16*   CA = (u16*)  alloc((size_t)BB*NN*DIM * 2);
    float* S  = (float*)alloc((size_t)ROWS * 4);
    u16* WTqkv = (u16*)alloc((size_t)DIM*3*DIM * 2);
    u16* WTo   = (u16*)alloc((size_t)DIM*DIM * 2);
    u16* WT1   = (u16*)alloc((size_t)DIM*MLPD * 2);
    u16* WT2   = (u16*)alloc((size_t)MLPD*DIM * 2);
    u16* WTl   = (u16*)alloc((size_t)DIM*RED * 2);
    u16* WTg   = (u16*)alloc((size_t)DIM*RED * 2);
    u16* WTc   = (u16*)alloc((size_t)RED*DIM * 2);

    copyf_kernel<<<XELEMS/256, 256, 0, stream>>>(x_in, XA);

    for (int l = 0; l < DEPTH; ++l) {
        wtrans_kernel<<<dim3(48,16), 256, 0, stream>>>(w_qkv + (size_t)l*DIM*3*DIM, WTqkv, DIM, 3*DIM);
        wtrans_kernel<<<dim3(16,16), 256, 0, stream>>>(w_o   + (size_t)l*DIM*DIM,   WTo,   DIM, DIM);
        wtrans_kernel<<<dim3(64,16), 256, 0, stream>>>(w1    + (size_t)l*DIM*MLPD,  WT1,   DIM, MLPD);
        wtrans_kernel<<<dim3(16,64), 256, 0, stream>>>(w2    + (size_t)l*MLPD*DIM,  WT2,   MLPD, DIM);
        wtrans_kernel<<<dim3(4,16),  256, 0, stream>>>(wl    + (size_t)l*DIM*RED,   WTl,   DIM, RED);
        wtrans_kernel<<<dim3(4,16),  256, 0, stream>>>(wg    + (size_t)l*DIM*RED,   WTg,   DIM, RED);
        wtrans_kernel<<<dim3(16,4),  256, 0, stream>>>(wc    + (size_t)l*RED*DIM,   WTc,   RED, DIM);

        // ---- attention block ----
        ln_kernel<<<ROWS/4, 256, 0, stream>>>(XA, ln1_g + l*DIM, ln1_b + l*DIM, (bf16*)L, ROWS);
        gemm_mfma<<<dim3(12,64), 256, 0, stream>>>(L, WTqkv, nullptr, nullptr, Q,
                                                   ROWS, 3*DIM, DIM, 0, 0);
        attn_mfma<<<BB*PP*HEADS, 256, 0, stream>>>(Q, L);
        gemm_mfma<<<dim3(4,64), 256, 0, stream>>>(L, WTo, b_o + l*DIM, XA, XB,
                                                  ROWS, DIM, DIM, 0, 1);

        // ---- MLP ----
        ln_kernel<<<ROWS/4, 256, 0, stream>>>(XB, ln2_g + l*DIM, ln2_b + l*DIM, (bf16*)Q, ROWS);
        gemm_mfma<<<dim3(16,64), 256, 0, stream>>>(Q, WT1, b1 + l*MLPD, nullptr, H,
                                                   ROWS, MLPD, DIM, 1, 0);
        gemm_mfma<<<dim3(4,64), 256, 0, stream>>>(H, WT2, b2 + l*DIM, nullptr, M1,
                                                  ROWS, DIM, MLPD, 0, 1);

        // ---- BiAttn ----
        ln_kernel<<<ROWS/4, 256, 0, stream>>>(M1, bn_g + l*DIM, bn_b + l*DIM, (bf16*)L, ROWS);
        mean_kernel<<<(BB*NN*DIM)/256, 256, 0, stream>>>((const bf16*)L, (bf16*)G);
        gemm_mfma<<<dim3(1,16), 256, 0, stream>>>(G, WTg, bg + l*RED, nullptr, G2,
                                                  BB*NN, RED, DIM, 1, 0);
        gemm_mfma<<<dim3(1,64), 256, 0, stream>>>(L, WTl, bl + l*RED, nullptr, XL,
                                                  ROWS, RED, DIM, 1, 0);
        gemm_mfma<<<dim3(4,16), 256, 0, stream>>>(G2, WTc, bc + l*DIM, nullptr, CA,
                                                  BB*NN, DIM, RED, 2, 0);
        sattn_kernel<<<ROWS/4, 256, 0, stream>>>((const bf16*)XL, (const bf16*)G2,
                                                 wsw + (size_t)l*2*RED, bsb + l, S);
        fuse_kernel<<<XELEMS/256, 256, 0, stream>>>(XB, M1, (const bf16*)CA, S, XA);
    }

    copyf_kernel<<<XELEMS/256, 256, 0, stream>>>(XA, (float*)d_out);
}

// Round 5
// 1210.004 us; speedup vs baseline: 4.0916x; 1.1376x over previous
//
#include <hip/hip_runtime.h>
#include <hip/hip_bf16.h>
#include <math.h>

typedef __hip_bfloat16 bf16;
typedef unsigned short u16;
typedef __bf16 bf16x8 __attribute__((ext_vector_type(8)));
typedef float f32x4 __attribute__((ext_vector_type(4)));

// ---------- helpers ----------
__device__ __forceinline__ float b2f(bf16 v) { return __bfloat162float(v); }
__device__ __forceinline__ bf16 f2b(float v) { return __float2bfloat16(v); }
__device__ __forceinline__ float bits2f(unsigned int u) {
    union { unsigned int i; float f; } w; w.i = u << 16; return w.f;
}
__device__ __forceinline__ u16 f2bits(float v) {
    union { bf16 h; u16 u; } w; w.h = __float2bfloat16(v); return w.u;
}
__device__ __forceinline__ void async16(void* lds, const void* g) {
    __builtin_amdgcn_global_load_lds(
        (const __attribute__((address_space(1))) unsigned int*)g,
        (__attribute__((address_space(3))) unsigned int*)lds, 16, 0, 0);
}

#define DEPTH 4
#define HEADS 8
#define DHEAD 64
#define DIM 512
#define MLPD 2048
#define RED 128
#define BB 8
#define PP 4
#define NN 256
#define ROWS (BB*PP*NN)          // 8192 tokens
#define XELEMS ((size_t)ROWS*DIM) // 4194304

// ---------- weight transpose+cast: W fp32 [K][N] -> WT bf16 [N][K] ----------
__global__ __launch_bounds__(256)
void wtrans_kernel(const float* __restrict__ W, u16* __restrict__ WT, int K, int N)
{
    __shared__ float T[32][33];
    const int tx = threadIdx.x & 31, ty = threadIdx.x >> 5; // ty 0..7
    const int n0 = blockIdx.x * 32, k0 = blockIdx.y * 32;
#pragma unroll
    for (int r = 0; r < 4; ++r)
        T[ty + r*8][tx] = W[(size_t)(k0 + ty + r*8) * N + n0 + tx];
    __syncthreads();
#pragma unroll
    for (int r = 0; r < 4; ++r)
        WT[(size_t)(n0 + ty + r*8) * K + k0 + tx] = f2bits(T[tx][ty + r*8]);
}

// ---------- templated MFMA GEMM: C = act(A @ WT^T + bias) [+res]
// A bf16 [M,K] row-major, WT bf16 [N,K] row-major.
// Grid: blockIdx.x = M-tile (XCD locality for A), blockIdx.y = N-tile.
// 256 threads = 4 waves in WROWS x WCOLS grid.
template<int BM, int BN, int BK, int WROWS, int WCOLS>
__global__ __launch_bounds__(256)
void gemm_t(const u16* __restrict__ A, const u16* __restrict__ WT,
            const float* __restrict__ bias, const float* __restrict__ res,
            void* __restrict__ Cv, int M, int N, int K, int act, int outf32)
{
    constexpr int KG  = BK/8;        // 16B k-groups per row
    constexpr int RPC = 512/BK;      // rows per 1KB staging chunk
    constexpr int NCA = BM*BK/512;   // A chunks
    constexpr int NCB = BN*BK/512;   // B chunks
    constexpr int CPT = (NCA+NCB)/4; // chunks per wave
    constexpr int WM = BM/WROWS, WN = BN/WCOLS;
    constexpr int AM = WM/16, AN = WN/16, KB = BK/32;

    __shared__ u16 As[BM*BK];
    __shared__ u16 Bs[BN*BK];
    const int tid = threadIdx.x, wave = tid >> 6, lane = tid & 63;
    const int bm = blockIdx.x * BM;
    const int bn = blockIdx.y * BN;
    const int wm = (wave / WCOLS) * WM, wn = (wave % WCOLS) * WN;
    const int lr = lane & 15, quad = lane >> 4;

    // staging: lane -> (row-in-chunk, swizzled source k-group)
    const int rowc = lane / KG;
    const int kgs  = ((lane & (KG-1)) ^ (KG == 4 ? ((rowc >> 1) & 3) : (rowc & 7))) * 8;

    f32x4 acc[AM][AN] = {};

    for (int k0 = 0; k0 < K; k0 += BK) {
        __syncthreads();
#pragma unroll
        for (int t = 0; t < CPT; ++t) {
            const int c = wave*CPT + t;
            if (c < NCA)
                async16(&As[c*512], A  + (size_t)(bm + c*RPC + rowc) * K + k0 + kgs);
            else
                async16(&Bs[(c-NCA)*512], WT + (size_t)(bn + (c-NCA)*RPC + rowc) * K + k0 + kgs);
        }
        __syncthreads();
        bf16x8 af[AM][KB], bv[AN][KB];
#pragma unroll
        for (int i = 0; i < AM; ++i) {
            const int rA = wm + i*16 + lr;
            const int sw = (KG == 4 ? (((rA & 15) >> 1) & 3) : (rA & 7));
#pragma unroll
            for (int kb = 0; kb < KB; ++kb)
                af[i][kb] = *(const bf16x8*)(As + rA*BK + (((kb*4 + quad) ^ sw) * 8));
        }
#pragma unroll
        for (int j = 0; j < AN; ++j) {
            const int rB = wn + j*16 + lr;
            const int sw = (KG == 4 ? (((rB & 15) >> 1) & 3) : (rB & 7));
#pragma unroll
            for (int kb = 0; kb < KB; ++kb)
                bv[j][kb] = *(const bf16x8*)(Bs + rB*BK + (((kb*4 + quad) ^ sw) * 8));
        }
#pragma unroll
        for (int i = 0; i < AM; ++i)
#pragma unroll
            for (int j = 0; j < AN; ++j)
#pragma unroll
                for (int kb = 0; kb < KB; ++kb)
                    acc[i][j] = __builtin_amdgcn_mfma_f32_16x16x32_bf16(
                        af[i][kb], bv[j][kb], acc[i][j], 0, 0, 0);
    }

#pragma unroll
    for (int i = 0; i < AM; ++i) {
        const int rowb = bm + wm + i*16 + quad*4;
#pragma unroll
        for (int j = 0; j < AN; ++j) {
            const int col = bn + wn + j*16 + lr;
            const float bvs = bias ? bias[col] : 0.f;
#pragma unroll
            for (int r = 0; r < 4; ++r) {
                float v = acc[i][j][r] + bvs;
                if (act == 1) v = 0.5f * v * (1.0f + erff(v * 0.70710678118f));
                else if (act == 2) v = 1.0f / (1.0f + __expf(-v));
                const size_t idx = (size_t)(rowb + r) * N + col;
                if (res) v += res[idx];
                if (outf32) ((float*)Cv)[idx] = v;
                else        ((u16*)Cv)[idx] = f2bits(v);
            }
        }
    }
}

// ---------- MFMA flash attention: one block per (b,p,h), wave = 64 query rows ----------
__global__ __launch_bounds__(256)
void attn_mfma(const u16* __restrict__ qkv, u16* __restrict__ out)
{
    __shared__ u16 Kt[64*72];        // K-tile [key][d], padded stride 72
    __shared__ u16 Vt[64*72];        // V-tile transposed [d][key], stride 72
    __shared__ u16 Pw[4][64*72];     // per-wave P tile [qrow][key], stride 72
    const int tid = threadIdx.x;
    const int wave = tid >> 6, lane = tid & 63;
    const int lr = lane & 15, quad = lane >> 4;
    const int bp = blockIdx.x >> 3, h = blockIdx.x & 7;
    const u16* base = qkv + (size_t)bp * NN * (3*DIM);
    const int qo = h*DHEAD, ko = DIM + h*DHEAD, vo = 2*DIM + h*DHEAD;
    const int m0 = wave * 64;

    bf16x8 qf[4][2];
#pragma unroll
    for (int i = 0; i < 4; ++i)
#pragma unroll
        for (int kb = 0; kb < 2; ++kb)
            qf[i][kb] = *(const bf16x8*)(base + (size_t)(m0 + i*16 + lr)*(3*DIM)
                                         + qo + kb*32 + quad*8);

    f32x4 o[4][4] = {};
    float mrow[4][4], lrow[4][4];
#pragma unroll
    for (int i = 0; i < 4; ++i)
#pragma unroll
        for (int r = 0; r < 4; ++r) { mrow[i][r] = -1e30f; lrow[i][r] = 0.f; }

    const int sr = tid >> 3, sc = tid & 7;

    for (int t = 0; t < 4; ++t) {
        __syncthreads();
#pragma unroll
        for (int half = 0; half < 2; ++half) {
            const int key = half*32 + sr;
            const u16* krow = base + (size_t)(t*64 + key)*(3*DIM);
            uint4 kv = *(const uint4*)(krow + ko + sc*8);
            *(uint4*)(Kt + key*72 + sc*8) = kv;
            uint4 vv = *(const uint4*)(krow + vo + sc*8);
            const int d0 = sc*8;
            Vt[(d0+0)*72 + key] = (u16)(vv.x & 0xffffu);
            Vt[(d0+1)*72 + key] = (u16)(vv.x >> 16);
            Vt[(d0+2)*72 + key] = (u16)(vv.y & 0xffffu);
            Vt[(d0+3)*72 + key] = (u16)(vv.y >> 16);
            Vt[(d0+4)*72 + key] = (u16)(vv.z & 0xffffu);
            Vt[(d0+5)*72 + key] = (u16)(vv.z >> 16);
            Vt[(d0+6)*72 + key] = (u16)(vv.w & 0xffffu);
            Vt[(d0+7)*72 + key] = (u16)(vv.w >> 16);
        }
        __syncthreads();

        f32x4 s[4][4] = {};
        bf16x8 kf[4][2];
#pragma unroll
        for (int j = 0; j < 4; ++j)
#pragma unroll
            for (int kb = 0; kb < 2; ++kb)
                kf[j][kb] = *(const bf16x8*)(Kt + (j*16 + lr)*72 + kb*32 + quad*8);
#pragma unroll
        for (int i = 0; i < 4; ++i)
#pragma unroll
            for (int j = 0; j < 4; ++j)
#pragma unroll
                for (int kb = 0; kb < 2; ++kb)
                    s[i][j] = __builtin_amdgcn_mfma_f32_16x16x32_bf16(
                        qf[i][kb], kf[j][kb], s[i][j], 0, 0, 0);

        float alpha[4][4];
#pragma unroll
        for (int i = 0; i < 4; ++i)
#pragma unroll
            for (int r = 0; r < 4; ++r) {
#pragma unroll
                for (int j = 0; j < 4; ++j) s[i][j][r] *= 0.125f;
                float mt = fmaxf(fmaxf(s[i][0][r], s[i][1][r]),
                                 fmaxf(s[i][2][r], s[i][3][r]));
#pragma unroll
                for (int off = 1; off <= 8; off <<= 1) mt = fmaxf(mt, __shfl_xor(mt, off));
                const float mn = fmaxf(mrow[i][r], mt);
                alpha[i][r] = __expf(mrow[i][r] - mn);
                mrow[i][r] = mn;
                float ssum = 0.f;
#pragma unroll
                for (int j = 0; j < 4; ++j) {
                    const float p = __expf(s[i][j][r] - mn);
                    s[i][j][r] = p; ssum += p;
                }
#pragma unroll
                for (int off = 1; off <= 8; off <<= 1) ssum += __shfl_xor(ssum, off);
                lrow[i][r] = lrow[i][r]*alpha[i][r] + ssum;
            }

#pragma unroll
        for (int i = 0; i < 4; ++i)
#pragma unroll
            for (int j = 0; j < 4; ++j)
#pragma unroll
                for (int r = 0; r < 4; ++r)
                    Pw[wave][(i*16 + quad*4 + r)*72 + j*16 + lr] = f2bits(s[i][j][r]);
        __syncthreads();

#pragma unroll
        for (int i = 0; i < 4; ++i)
#pragma unroll
            for (int jd = 0; jd < 4; ++jd)
#pragma unroll
                for (int r = 0; r < 4; ++r) o[i][jd][r] *= alpha[i][r];

        bf16x8 af[4][2], bv[4][2];
#pragma unroll
        for (int i = 0; i < 4; ++i)
#pragma unroll
            for (int kb = 0; kb < 2; ++kb)
                af[i][kb] = *(const bf16x8*)(Pw[wave] + (i*16 + lr)*72 + kb*32 + quad*8);
#pragma unroll
        for (int jd = 0; jd < 4; ++jd)
#pragma unroll
            for (int kb = 0; kb < 2; ++kb)
                bv[jd][kb] = *(const bf16x8*)(Vt + (jd*16 + lr)*72 + kb*32 + quad*8);
#pragma unroll
        for (int i = 0; i < 4; ++i)
#pragma unroll
            for (int jd = 0; jd < 4; ++jd)
#pragma unroll
                for (int kb = 0; kb < 2; ++kb)
                    o[i][jd] = __builtin_amdgcn_mfma_f32_16x16x32_bf16(
                        af[i][kb], bv[jd][kb], o[i][jd], 0, 0, 0);
    }

#pragma unroll
    for (int i = 0; i < 4; ++i)
#pragma unroll
        for (int r = 0; r < 4; ++r) {
            const float inv = 1.0f / lrow[i][r];
            const size_t rowg = (size_t)bp*NN + m0 + i*16 + quad*4 + r;
#pragma unroll
            for (int jd = 0; jd < 4; ++jd)
                out[rowg*DIM + h*DHEAD + jd*16 + lr] = f2bits(o[i][jd][r] * inv);
        }
}

// ---------- LayerNorm over DIM=512, input fp32, params fp32, output bf16 ----------
__global__ __launch_bounds__(256)
void ln_kernel(const float* __restrict__ x, const float* __restrict__ g,
               const float* __restrict__ b, bf16* __restrict__ y, int rows)
{
    const int wave = threadIdx.x >> 6;
    const int lane = threadIdx.x & 63;
    const int row = blockIdx.x * 4 + wave;
    if (row >= rows) return;
    const float* xr = x + (size_t)row * DIM;
    float v[8]; float s = 0.f, s2 = 0.f;
#pragma unroll
    for (int i = 0; i < 8; ++i) {
        v[i] = xr[lane + 64*i];
        s += v[i]; s2 += v[i]*v[i];
    }
#pragma unroll
    for (int off = 32; off; off >>= 1) { s += __shfl_xor(s, off); s2 += __shfl_xor(s2, off); }
    const float mean = s * (1.f/512.f);
    const float var  = s2 * (1.f/512.f) - mean*mean;
    const float rstd = rsqrtf(var + 1e-5f);
    bf16* yr = y + (size_t)row * DIM;
#pragma unroll
    for (int i = 0; i < 8; ++i) {
        const int d = lane + 64*i;
        yr[d] = f2b((v[i]-mean)*rstd*g[d] + b[d]);
    }
}

// ---------- mean over P of LN'd x: [b,p,n,d] -> [b,n,d] ----------
__global__ void mean_kernel(const bf16* __restrict__ L, bf16* __restrict__ G)
{
    const int idx = blockIdx.x * 256 + threadIdx.x;  // < 8*256*512
    const int b = idx >> 17;
    const int rem = idx & 131071;
    float s = 0.f;
#pragma unroll
    for (int p = 0; p < PP; ++p)
        s += b2f(L[((size_t)b*PP + p)*131072 + rem]);
    G[idx] = f2b(0.25f * s);
}

// ---------- s_attn: sigmoid( [xl, xg] . ws + bs ), one wave per row ----------
__global__ __launch_bounds__(256)
void sattn_kernel(const bf16* __restrict__ xl, const bf16* __restrict__ xg,
                  const float* __restrict__ wsv, const float* __restrict__ bs,
                  float* __restrict__ S)
{
    const int wave = threadIdx.x >> 6, lane = threadIdx.x & 63;
    const int row = blockIdx.x * 4 + wave;  // 0..8191
    const int b = row >> 10;
    const int n = row & 255;
    const bf16* xlr = xl + (size_t)row * RED;
    const bf16* xgr = xg + ((size_t)b*NN + n) * RED;
    float s = b2f(xlr[lane])    * wsv[lane]
            + b2f(xlr[lane+64]) * wsv[lane+64]
            + b2f(xgr[lane])    * wsv[RED+lane]
            + b2f(xgr[lane+64]) * wsv[RED+64+lane];
#pragma unroll
    for (int off = 32; off; off >>= 1) s += __shfl_xor(s, off);
    if (lane == 0) S[row] = 1.f / (1.f + __expf(-(s + bs[0])));
}

// ---------- fuse: x_new = x_attn_res + mlp_out * c_attn * s_attn ----------
__global__ void fuse_kernel(const float* __restrict__ xb, const float* __restrict__ m1,
                            const bf16* __restrict__ ca, const float* __restrict__ S,
                            float* __restrict__ xa)
{
    const int idx = blockIdx.x * 256 + threadIdx.x;  // < 4194304
    const int r = idx >> 9;
    const int d = idx & 511;
    const int b = r >> 10;
    const int n = r & 255;
    xa[idx] = xb[idx] + m1[idx] * b2f(ca[(((size_t)b << 8) + n)*DIM + d]) * S[r];
}

__global__ void copyf_kernel(const float* __restrict__ in, float* __restrict__ out)
{
    const int idx = blockIdx.x * 256 + threadIdx.x;
    out[idx] = in[idx];
}

// ---------- host launch ----------
extern "C" void kernel_launch(void* const* d_in, const int* in_sizes, int n_in,
                              void* d_out, int out_size, void* d_ws, size_t ws_size,
                              hipStream_t stream)
{
    const float* x_in  = (const float*)d_in[0];
    const float* ln1_g = (const float*)d_in[1];
    const float* ln1_b = (const float*)d_in[2];
    const float* w_qkv = (const float*)d_in[3];
    const float* w_o   = (const float*)d_in[4];
    const float* b_o   = (const float*)d_in[5];
    const float* ln2_g = (const float*)d_in[6];
    const float* ln2_b = (const float*)d_in[7];
    const float* w1    = (const float*)d_in[8];
    const float* b1    = (const float*)d_in[9];
    const float* w2    = (const float*)d_in[10];
    const float* b2    = (const float*)d_in[11];
    const float* bn_g  = (const float*)d_in[12];
    const float* bn_b  = (const float*)d_in[13];
    const float* wg    = (const float*)d_in[14];
    const float* bg    = (const float*)d_in[15];
    const float* wl    = (const float*)d_in[16];
    const float* bl    = (const float*)d_in[17];
    const float* wc    = (const float*)d_in[18];
    const float* bc    = (const float*)d_in[19];
    const float* wsw   = (const float*)d_in[20];
    const float* bsb   = (const float*)d_in[21];

    char* ws = (char*)d_ws;
    auto alloc = [&](size_t bytes) {
        char* p = ws;
        ws += (bytes + 255) & ~(size_t)255;
        return p;
    };
    float* XA = (float*)alloc(XELEMS * 4);
    float* XB = (float*)alloc(XELEMS * 4);
    float* M1 = (float*)alloc(XELEMS * 4);
    u16*   L  = (u16*)  alloc(XELEMS * 2);
    u16*   Q  = (u16*)  alloc((size_t)ROWS * 3*DIM * 2);
    u16*   H  = (u16*)  alloc((size_t)ROWS * MLPD * 2);
    u16*   G  = (u16*)  alloc((size_t)BB*NN*DIM * 2);
    u16*   G2 = (u16*)  alloc((size_t)BB*NN*RED * 2);
    u16*   XL = (u16*)  alloc((size_t)ROWS*RED * 2);
    u16*   CA = (u16*)  alloc((size_t)BB*NN*DIM * 2);
    float* S  = (float*)alloc((size_t)ROWS * 4);
    u16* WTqkv = (u16*)alloc((size_t)DIM*3*DIM * 2);
    u16* WTo   = (u16*)alloc((size_t)DIM*DIM * 2);
    u16* WT1   = (u16*)alloc((size_t)DIM*MLPD * 2);
    u16* WT2   = (u16*)alloc((size_t)MLPD*DIM * 2);
    u16* WTl   = (u16*)alloc((size_t)DIM*RED * 2);
    u16* WTg   = (u16*)alloc((size_t)DIM*RED * 2);
    u16* WTc   = (u16*)alloc((size_t)RED*DIM * 2);

    copyf_kernel<<<XELEMS/256, 256, 0, stream>>>(x_in, XA);

    for (int l = 0; l < DEPTH; ++l) {
        wtrans_kernel<<<dim3(48,16), 256, 0, stream>>>(w_qkv + (size_t)l*DIM*3*DIM, WTqkv, DIM, 3*DIM);
        wtrans_kernel<<<dim3(16,16), 256, 0, stream>>>(w_o   + (size_t)l*DIM*DIM,   WTo,   DIM, DIM);
        wtrans_kernel<<<dim3(64,16), 256, 0, stream>>>(w1    + (size_t)l*DIM*MLPD,  WT1,   DIM, MLPD);
        wtrans_kernel<<<dim3(16,64), 256, 0, stream>>>(w2    + (size_t)l*MLPD*DIM,  WT2,   MLPD, DIM);
        wtrans_kernel<<<dim3(4,16),  256, 0, stream>>>(wl    + (size_t)l*DIM*RED,   WTl,   DIM, RED);
        wtrans_kernel<<<dim3(4,16),  256, 0, stream>>>(wg    + (size_t)l*DIM*RED,   WTg,   DIM, RED);
        wtrans_kernel<<<dim3(16,4),  256, 0, stream>>>(wc    + (size_t)l*RED*DIM,   WTc,   RED, DIM);

        // ---- attention block ----
        ln_kernel<<<ROWS/4, 256, 0, stream>>>(XA, ln1_g + l*DIM, ln1_b + l*DIM, (bf16*)L, ROWS);
        gemm_t<128,128,32,2,2><<<dim3(64,12), 256, 0, stream>>>(
            L, WTqkv, nullptr, nullptr, Q, ROWS, 3*DIM, DIM, 0, 0);
        attn_mfma<<<BB*PP*HEADS, 256, 0, stream>>>(Q, L);
        gemm_t<128,128,64,2,2><<<dim3(64,4), 256, 0, stream>>>(
            L, WTo, b_o + l*DIM, XA, XB, ROWS, DIM, DIM, 0, 1);

        // ---- MLP ----
        ln_kernel<<<ROWS/4, 256, 0, stream>>>(XB, ln2_g + l*DIM, ln2_b + l*DIM, (bf16*)Q, ROWS);
        gemm_t<128,128,32,2,2><<<dim3(64,16), 256, 0, stream>>>(
            Q, WT1, b1 + l*MLPD, nullptr, H, ROWS, MLPD, DIM, 1, 0);
        gemm_t<128,128,64,2,2><<<dim3(64,4), 256, 0, stream>>>(
            H, WT2, b2 + l*DIM, nullptr, M1, ROWS, DIM, MLPD, 0, 1);

        // ---- BiAttn ----
        ln_kernel<<<ROWS/4, 256, 0, stream>>>(M1, bn_g + l*DIM, bn_b + l*DIM, (bf16*)L, ROWS);
        mean_kernel<<<(BB*NN*DIM)/256, 256, 0, stream>>>((const bf16*)L, (bf16*)G);
        gemm_t<64,64,64,2,2><<<dim3(32,2), 256, 0, stream>>>(
            G, WTg, bg + l*RED, nullptr, G2, BB*NN, RED, DIM, 1, 0);
        gemm_t<64,64,64,2,2><<<dim3(128,2), 256, 0, stream>>>(
            L, WTl, bl + l*RED, nullptr, XL, ROWS, RED, DIM, 1, 0);
        gemm_t<64,64,64,2,2><<<dim3(32,8), 256, 0, stream>>>(
            G2, WTc, bc + l*DIM, nullptr, CA, BB*NN, DIM, RED, 2, 0);
        sattn_kernel<<<ROWS/4, 256, 0, stream>>>((const bf16*)XL, (const bf16*)G2,
                                                 wsw + (size_t)l*2*RED, bsb + l, S);
        fuse_kernel<<<XELEMS/256, 256, 0, stream>>>(XB, M1, (const bf16*)CA, S, XA);
    }

    copyf_kernel<<<XELEMS/256, 256, 0, stream>>>(XA, (float*)d_out);
}

// Round 6
// 1040.101 us; speedup vs baseline: 4.7600x; 1.1634x over previous
//
#include <hip/hip_runtime.h>
#include <hip/hip_bf16.h>
#include <math.h>

typedef __hip_bfloat16 bf16;
typedef unsigned short u16;
typedef __bf16 bf16x8 __attribute__((ext_vector_type(8)));
typedef float f32x4 __attribute__((ext_vector_type(4)));

// ---------- helpers ----------
__device__ __forceinline__ float b2f(bf16 v) { return __bfloat162float(v); }
__device__ __forceinline__ bf16 f2b(float v) { return __float2bfloat16(v); }
__device__ __forceinline__ float bits2f(unsigned int u) {
    union { unsigned int i; float f; } w; w.i = u << 16; return w.f;
}
__device__ __forceinline__ u16 f2bits(float v) {
    union { bf16 h; u16 u; } w; w.h = __float2bfloat16(v); return w.u;
}
__device__ __forceinline__ void async16(void* lds, const void* g) {
    __builtin_amdgcn_global_load_lds(
        (const __attribute__((address_space(1))) unsigned int*)g,
        (__attribute__((address_space(3))) unsigned int*)lds, 16, 0, 0);
}

#define DEPTH 4
#define HEADS 8
#define DHEAD 64
#define DIM 512
#define MLPD 2048
#define RED 128
#define BB 8
#define PP 4
#define NN 256
#define ROWS (BB*PP*NN)          // 8192 tokens
#define XELEMS ((size_t)ROWS*DIM) // 4194304

// ---------- batched weight transpose+cast: W fp32 [D][K][N] -> WT bf16 [D][N][K] ----------
__global__ __launch_bounds__(256)
void wtrans_all(const float* __restrict__ W, u16* __restrict__ WT, int K, int N)
{
    __shared__ float T[32][33];
    const int l = blockIdx.z;
    W  += (size_t)l * K * N;
    WT += (size_t)l * N * K;
    const int tx = threadIdx.x & 31, ty = threadIdx.x >> 5; // ty 0..7
    const int n0 = blockIdx.x * 32, k0 = blockIdx.y * 32;
#pragma unroll
    for (int r = 0; r < 4; ++r)
        T[ty + r*8][tx] = W[(size_t)(k0 + ty + r*8) * N + n0 + tx];
    __syncthreads();
#pragma unroll
    for (int r = 0; r < 4; ++r)
        WT[(size_t)(n0 + ty + r*8) * K + k0 + tx] = f2bits(T[tx][ty + r*8]);
}

// ---------- double-buffered MFMA GEMM: C = act(A @ WT^T + bias) [+res]
// A bf16 [M,K] row-major, WT bf16 [N,K] row-major.
// Grid: blockIdx.x = M-tile (XCD locality for A), blockIdx.y = N-tile.
template<int BM, int BN, int BK, int WROWS, int WCOLS>
__global__ __launch_bounds__(256)
void gemm_db(const u16* __restrict__ A, const u16* __restrict__ WT,
             const float* __restrict__ bias, const float* __restrict__ res,
             void* __restrict__ Cv, int M, int N, int K, int act, int outf32)
{
    constexpr int KG  = BK/8;        // 16B k-groups per row
    constexpr int RPC = 512/BK;      // rows per 1KB staging chunk
    constexpr int NCA = BM*BK/512;   // A chunks
    constexpr int NCB = BN*BK/512;   // B chunks
    constexpr int CPT = (NCA+NCB)/4; // chunks per wave
    constexpr int WM = BM/WROWS, WN = BN/WCOLS;
    constexpr int AM = WM/16, AN = WN/16, KB = BK/32;

    __shared__ u16 As[2][BM*BK];
    __shared__ u16 Bs[2][BN*BK];
    const int tid = threadIdx.x, wave = tid >> 6, lane = tid & 63;
    const int bm = blockIdx.x * BM;
    const int bn = blockIdx.y * BN;
    const int wm = (wave / WCOLS) * WM, wn = (wave % WCOLS) * WN;
    const int lr = lane & 15, quad = lane >> 4;

    // staging: lane -> (row-in-chunk, swizzled source k-group)
    const int rowc = lane / KG;
    const int kgs  = ((lane & (KG-1)) ^ (KG == 4 ? ((rowc >> 1) & 3) : (rowc & 7))) * 8;

    auto stage = [&](int buf, int k0) {
#pragma unroll
        for (int t = 0; t < CPT; ++t) {
            const int c = wave*CPT + t;
            if (c < NCA)
                async16(&As[buf][c*512], A  + (size_t)(bm + c*RPC + rowc) * K + k0 + kgs);
            else
                async16(&Bs[buf][(c-NCA)*512], WT + (size_t)(bn + (c-NCA)*RPC + rowc) * K + k0 + kgs);
        }
    };

    f32x4 acc[AM][AN] = {};

    stage(0, 0);
    __syncthreads();   // drains tile 0

    const int NK = K / BK;
    for (int ki = 0; ki < NK; ++ki) {
        const int cur = ki & 1;
        if (ki + 1 < NK) stage(cur ^ 1, (ki + 1) * BK);   // prefetch while computing

        bf16x8 af[AM][KB], bv[AN][KB];
#pragma unroll
        for (int i = 0; i < AM; ++i) {
            const int rA = wm + i*16 + lr;
            const int sw = (KG == 4 ? (((rA & 15) >> 1) & 3) : (rA & 7));
#pragma unroll
            for (int kb = 0; kb < KB; ++kb)
                af[i][kb] = *(const bf16x8*)(As[cur] + rA*BK + (((kb*4 + quad) ^ sw) * 8));
        }
#pragma unroll
        for (int j = 0; j < AN; ++j) {
            const int rB = wn + j*16 + lr;
            const int sw = (KG == 4 ? (((rB & 15) >> 1) & 3) : (rB & 7));
#pragma unroll
            for (int kb = 0; kb < KB; ++kb)
                bv[j][kb] = *(const bf16x8*)(Bs[cur] + rB*BK + (((kb*4 + quad) ^ sw) * 8));
        }
#pragma unroll
        for (int i = 0; i < AM; ++i)
#pragma unroll
            for (int j = 0; j < AN; ++j)
#pragma unroll
                for (int kb = 0; kb < KB; ++kb)
                    acc[i][j] = __builtin_amdgcn_mfma_f32_16x16x32_bf16(
                        af[i][kb], bv[j][kb], acc[i][j], 0, 0, 0);
        __syncthreads();   // drains prefetch; protects cur for overwrite next iter
    }

#pragma unroll
    for (int i = 0; i < AM; ++i) {
        const int rowb = bm + wm + i*16 + quad*4;
#pragma unroll
        for (int j = 0; j < AN; ++j) {
            const int col = bn + wn + j*16 + lr;
            const float bvs = bias ? bias[col] : 0.f;
#pragma unroll
            for (int r = 0; r < 4; ++r) {
                float v = acc[i][j][r] + bvs;
                if (act == 1) v = 0.5f * v * (1.0f + erff(v * 0.70710678118f));
                else if (act == 2) v = 1.0f / (1.0f + __expf(-v));
                const size_t idx = (size_t)(rowb + r) * N + col;
                if (res) v += res[idx];
                if (outf32) ((float*)Cv)[idx] = v;
                else        ((u16*)Cv)[idx] = f2bits(v);
            }
        }
    }
}

// ---------- MFMA flash attention: one block per (b,p,h), wave = 64 query rows ----------
__global__ __launch_bounds__(256)
void attn_mfma(const u16* __restrict__ qkv, u16* __restrict__ out)
{
    __shared__ u16 Kt[64*72];
    __shared__ u16 Vt[64*72];
    __shared__ u16 Pw[4][64*72];
    const int tid = threadIdx.x;
    const int wave = tid >> 6, lane = tid & 63;
    const int lr = lane & 15, quad = lane >> 4;
    const int bp = blockIdx.x >> 3, h = blockIdx.x & 7;
    const u16* base = qkv + (size_t)bp * NN * (3*DIM);
    const int qo = h*DHEAD, ko = DIM + h*DHEAD, vo = 2*DIM + h*DHEAD;
    const int m0 = wave * 64;

    bf16x8 qf[4][2];
#pragma unroll
    for (int i = 0; i < 4; ++i)
#pragma unroll
        for (int kb = 0; kb < 2; ++kb)
            qf[i][kb] = *(const bf16x8*)(base + (size_t)(m0 + i*16 + lr)*(3*DIM)
                                         + qo + kb*32 + quad*8);

    f32x4 o[4][4] = {};
    float mrow[4][4], lrow[4][4];
#pragma unroll
    for (int i = 0; i < 4; ++i)
#pragma unroll
        for (int r = 0; r < 4; ++r) { mrow[i][r] = -1e30f; lrow[i][r] = 0.f; }

    const int sr = tid >> 3, sc = tid & 7;

    for (int t = 0; t < 4; ++t) {
        __syncthreads();
#pragma unroll
        for (int half = 0; half < 2; ++half) {
            const int key = half*32 + sr;
            const u16* krow = base + (size_t)(t*64 + key)*(3*DIM);
            uint4 kv = *(const uint4*)(krow + ko + sc*8);
            *(uint4*)(Kt + key*72 + sc*8) = kv;
            uint4 vv = *(const uint4*)(krow + vo + sc*8);
            const int d0 = sc*8;
            Vt[(d0+0)*72 + key] = (u16)(vv.x & 0xffffu);
            Vt[(d0+1)*72 + key] = (u16)(vv.x >> 16);
            Vt[(d0+2)*72 + key] = (u16)(vv.y & 0xffffu);
            Vt[(d0+3)*72 + key] = (u16)(vv.y >> 16);
            Vt[(d0+4)*72 + key] = (u16)(vv.z & 0xffffu);
            Vt[(d0+5)*72 + key] = (u16)(vv.z >> 16);
            Vt[(d0+6)*72 + key] = (u16)(vv.w & 0xffffu);
            Vt[(d0+7)*72 + key] = (u16)(vv.w >> 16);
        }
        __syncthreads();

        f32x4 s[4][4] = {};
        bf16x8 kf[4][2];
#pragma unroll
        for (int j = 0; j < 4; ++j)
#pragma unroll
            for (int kb = 0; kb < 2; ++kb)
                kf[j][kb] = *(const bf16x8*)(Kt + (j*16 + lr)*72 + kb*32 + quad*8);
#pragma unroll
        for (int i = 0; i < 4; ++i)
#pragma unroll
            for (int j = 0; j < 4; ++j)
#pragma unroll
                for (int kb = 0; kb < 2; ++kb)
                    s[i][j] = __builtin_amdgcn_mfma_f32_16x16x32_bf16(
                        qf[i][kb], kf[j][kb], s[i][j], 0, 0, 0);

        float alpha[4][4];
#pragma unroll
        for (int i = 0; i < 4; ++i)
#pragma unroll
            for (int r = 0; r < 4; ++r) {
#pragma unroll
                for (int j = 0; j < 4; ++j) s[i][j][r] *= 0.125f;
                float mt = fmaxf(fmaxf(s[i][0][r], s[i][1][r]),
                                 fmaxf(s[i][2][r], s[i][3][r]));
#pragma unroll
                for (int off = 1; off <= 8; off <<= 1) mt = fmaxf(mt, __shfl_xor(mt, off));
                const float mn = fmaxf(mrow[i][r], mt);
                alpha[i][r] = __expf(mrow[i][r] - mn);
                mrow[i][r] = mn;
                float ssum = 0.f;
#pragma unroll
                for (int j = 0; j < 4; ++j) {
                    const float p = __expf(s[i][j][r] - mn);
                    s[i][j][r] = p; ssum += p;
                }
#pragma unroll
                for (int off = 1; off <= 8; off <<= 1) ssum += __shfl_xor(ssum, off);
                lrow[i][r] = lrow[i][r]*alpha[i][r] + ssum;
            }

#pragma unroll
        for (int i = 0; i < 4; ++i)
#pragma unroll
            for (int j = 0; j < 4; ++j)
#pragma unroll
                for (int r = 0; r < 4; ++r)
                    Pw[wave][(i*16 + quad*4 + r)*72 + j*16 + lr] = f2bits(s[i][j][r]);
        __syncthreads();

#pragma unroll
        for (int i = 0; i < 4; ++i)
#pragma unroll
            for (int jd = 0; jd < 4; ++jd)
#pragma unroll
                for (int r = 0; r < 4; ++r) o[i][jd][r] *= alpha[i][r];

        bf16x8 af[4][2], bv[4][2];
#pragma unroll
        for (int i = 0; i < 4; ++i)
#pragma unroll
            for (int kb = 0; kb < 2; ++kb)
                af[i][kb] = *(const bf16x8*)(Pw[wave] + (i*16 + lr)*72 + kb*32 + quad*8);
#pragma unroll
        for (int jd = 0; jd < 4; ++jd)
#pragma unroll
            for (int kb = 0; kb < 2; ++kb)
                bv[jd][kb] = *(const bf16x8*)(Vt + (jd*16 + lr)*72 + kb*32 + quad*8);
#pragma unroll
        for (int i = 0; i < 4; ++i)
#pragma unroll
            for (int jd = 0; jd < 4; ++jd)
#pragma unroll
                for (int kb = 0; kb < 2; ++kb)
                    o[i][jd] = __builtin_amdgcn_mfma_f32_16x16x32_bf16(
                        af[i][kb], bv[jd][kb], o[i][jd], 0, 0, 0);
    }

#pragma unroll
    for (int i = 0; i < 4; ++i)
#pragma unroll
        for (int r = 0; r < 4; ++r) {
            const float inv = 1.0f / lrow[i][r];
            const size_t rowg = (size_t)bp*NN + m0 + i*16 + quad*4 + r;
#pragma unroll
            for (int jd = 0; jd < 4; ++jd)
                out[rowg*DIM + h*DHEAD + jd*16 + lr] = f2bits(o[i][jd][r] * inv);
        }
}

// ---------- LayerNorm over DIM=512, fp32 in, bf16 out; one wave per row; float4 ----------
__global__ __launch_bounds__(256)
void ln_kernel(const float* __restrict__ x, const float* __restrict__ g,
               const float* __restrict__ b, u16* __restrict__ y, int rows)
{
    const int wave = threadIdx.x >> 6, lane = threadIdx.x & 63;
    const int row = blockIdx.x * 4 + wave;
    if (row >= rows) return;
    const float4* xr = (const float4*)(x + (size_t)row * DIM);
    float4 v0 = xr[lane], v1 = xr[lane + 64];
    float s  = v0.x+v0.y+v0.z+v0.w + v1.x+v1.y+v1.z+v1.w;
    float s2 = v0.x*v0.x+v0.y*v0.y+v0.z*v0.z+v0.w*v0.w
             + v1.x*v1.x+v1.y*v1.y+v1.z*v1.z+v1.w*v1.w;
#pragma unroll
    for (int off = 32; off; off >>= 1) { s += __shfl_xor(s, off); s2 += __shfl_xor(s2, off); }
    const float mean = s * (1.f/512.f);
    const float var  = s2 * (1.f/512.f) - mean*mean;
    const float rstd = rsqrtf(var + 1e-5f);
    const float4* gp = (const float4*)g; const float4* bp = (const float4*)b;
    float4 g0 = gp[lane], g1 = gp[lane+64], b0 = bp[lane], b1 = bp[lane+64];
    ushort4 o0, o1;
    o0.x = f2bits((v0.x-mean)*rstd*g0.x + b0.x);
    o0.y = f2bits((v0.y-mean)*rstd*g0.y + b0.y);
    o0.z = f2bits((v0.z-mean)*rstd*g0.z + b0.z);
    o0.w = f2bits((v0.w-mean)*rstd*g0.w + b0.w);
    o1.x = f2bits((v1.x-mean)*rstd*g1.x + b1.x);
    o1.y = f2bits((v1.y-mean)*rstd*g1.y + b1.y);
    o1.z = f2bits((v1.z-mean)*rstd*g1.z + b1.z);
    o1.w = f2bits((v1.w-mean)*rstd*g1.w + b1.w);
    ushort4* yr = (ushort4*)(y + (size_t)row * DIM);
    yr[lane] = o0; yr[lane+64] = o1;
}

// ---------- mean over P: [b,p,n,d] -> [b,n,d], 4 elems/thread ----------
__global__ void mean_kernel(const u16* __restrict__ L, u16* __restrict__ G)
{
    const int idx = blockIdx.x * 256 + threadIdx.x;   // < 8*256*512/4
    const int b = idx >> 15;
    const int rem = idx & 32767;
    float a0 = 0.f, a1 = 0.f, a2 = 0.f, a3 = 0.f;
#pragma unroll
    for (int p = 0; p < PP; ++p) {
        ushort4 u = *(const ushort4*)(L + ((size_t)b*PP + p)*131072 + rem*4);
        a0 += bits2f(u.x); a1 += bits2f(u.y); a2 += bits2f(u.z); a3 += bits2f(u.w);
    }
    ushort4 o;
    o.x = f2bits(0.25f*a0); o.y = f2bits(0.25f*a1);
    o.z = f2bits(0.25f*a2); o.w = f2bits(0.25f*a3);
    *(ushort4*)(G + (size_t)idx*4) = o;
}

// ---------- s_attn: sigmoid( [xl, xg] . ws + bs ), one wave per row ----------
__global__ __launch_bounds__(256)
void sattn_kernel(const u16* __restrict__ xl, const u16* __restrict__ xg,
                  const float* __restrict__ wsv, const float* __restrict__ bs,
                  float* __restrict__ S)
{
    const int wave = threadIdx.x >> 6, lane = threadIdx.x & 63;
    const int row = blockIdx.x * 4 + wave;
    const int b = row >> 10;
    const int n = row & 255;
    const u16* xlr = xl + (size_t)row * RED;
    const u16* xgr = xg + ((size_t)b*NN + n) * RED;
    float s = bits2f(xlr[lane])    * wsv[lane]
            + bits2f(xlr[lane+64]) * wsv[lane+64]
            + bits2f(xgr[lane])    * wsv[RED+lane]
            + bits2f(xgr[lane+64]) * wsv[RED+64+lane];
#pragma unroll
    for (int off = 32; off; off >>= 1) s += __shfl_xor(s, off);
    if (lane == 0) S[row] = 1.f / (1.f + __expf(-(s + bs[0])));
}

// ---------- fuse: x_new = x_attn_res + mlp_out * c_attn * s_attn (4 elems/thread) ----------
__global__ void fuse_kernel(const float4* __restrict__ xb, const float4* __restrict__ m1,
                            const u16* __restrict__ ca, const float* __restrict__ S,
                            float4* __restrict__ xa)
{
    const int idx = blockIdx.x * 256 + threadIdx.x;   // < XELEMS/4
    const int r = idx >> 7;          // 128 float4-groups per row
    const int dg = idx & 127;
    const int b = r >> 10;
    const int n = r & 255;
    const float s = S[r];
    ushort4 cu = *(const ushort4*)(ca + ((((size_t)b << 8) + n)*DIM) + dg*4);
    float4 xv = xb[idx], mv = m1[idx], o;
    o.x = xv.x + mv.x * bits2f(cu.x) * s;
    o.y = xv.y + mv.y * bits2f(cu.y) * s;
    o.z = xv.z + mv.z * bits2f(cu.z) * s;
    o.w = xv.w + mv.w * bits2f(cu.w) * s;
    xa[idx] = o;
}

__global__ void copyf4_kernel(const float4* __restrict__ in, float4* __restrict__ out)
{
    const int idx = blockIdx.x * 256 + threadIdx.x;
    out[idx] = in[idx];
}

// ---------- host launch ----------
extern "C" void kernel_launch(void* const* d_in, const int* in_sizes, int n_in,
                              void* d_out, int out_size, void* d_ws, size_t ws_size,
                              hipStream_t stream)
{
    const float* x_in  = (const float*)d_in[0];
    const float* ln1_g = (const float*)d_in[1];
    const float* ln1_b = (const float*)d_in[2];
    const float* w_qkv = (const float*)d_in[3];
    const float* w_o   = (const float*)d_in[4];
    const float* b_o   = (const float*)d_in[5];
    const float* ln2_g = (const float*)d_in[6];
    const float* ln2_b = (const float*)d_in[7];
    const float* w1    = (const float*)d_in[8];
    const float* b1    = (const float*)d_in[9];
    const float* w2    = (const float*)d_in[10];
    const float* b2    = (const float*)d_in[11];
    const float* bn_g  = (const float*)d_in[12];
    const float* bn_b  = (const float*)d_in[13];
    const float* wg    = (const float*)d_in[14];
    const float* bg    = (const float*)d_in[15];
    const float* wl    = (const float*)d_in[16];
    const float* bl    = (const float*)d_in[17];
    const float* wc    = (const float*)d_in[18];
    const float* bc    = (const float*)d_in[19];
    const float* wsw   = (const float*)d_in[20];
    const float* bsb   = (const float*)d_in[21];

    char* ws = (char*)d_ws;
    auto alloc = [&](size_t bytes) {
        char* p = ws;
        ws += (bytes + 255) & ~(size_t)255;
        return p;
    };
    float* XA = (float*)alloc(XELEMS * 4);
    float* XB = (float*)alloc(XELEMS * 4);
    float* M1 = (float*)alloc(XELEMS * 4);
    u16*   L  = (u16*)  alloc(XELEMS * 2);
    u16*   Q  = (u16*)  alloc((size_t)ROWS * 3*DIM * 2);
    u16*   H  = (u16*)  alloc((size_t)ROWS * MLPD * 2);
    u16*   G  = (u16*)  alloc((size_t)BB*NN*DIM * 2);
    u16*   G2 = (u16*)  alloc((size_t)BB*NN*RED * 2);
    u16*   XL = (u16*)  alloc((size_t)ROWS*RED * 2);
    u16*   CA = (u16*)  alloc((size_t)BB*NN*DIM * 2);
    float* S  = (float*)alloc((size_t)ROWS * 4);
    // all-layer transposed bf16 weights
    u16* WTqkv = (u16*)alloc((size_t)DEPTH*DIM*3*DIM * 2);
    u16* WTo   = (u16*)alloc((size_t)DEPTH*DIM*DIM * 2);
    u16* WT1   = (u16*)alloc((size_t)DEPTH*DIM*MLPD * 2);
    u16* WT2   = (u16*)alloc((size_t)DEPTH*MLPD*DIM * 2);
    u16* WTl   = (u16*)alloc((size_t)DEPTH*DIM*RED * 2);
    u16* WTg   = (u16*)alloc((size_t)DEPTH*DIM*RED * 2);
    u16* WTc   = (u16*)alloc((size_t)DEPTH*RED*DIM * 2);

    // ---- all weight transposes upfront, batched over depth ----
    wtrans_all<<<dim3(48,16,DEPTH), 256, 0, stream>>>(w_qkv, WTqkv, DIM, 3*DIM);
    wtrans_all<<<dim3(16,16,DEPTH), 256, 0, stream>>>(w_o,   WTo,   DIM, DIM);
    wtrans_all<<<dim3(64,16,DEPTH), 256, 0, stream>>>(w1,    WT1,   DIM, MLPD);
    wtrans_all<<<dim3(16,64,DEPTH), 256, 0, stream>>>(w2,    WT2,   MLPD, DIM);
    wtrans_all<<<dim3(4,16,DEPTH),  256, 0, stream>>>(wl,    WTl,   DIM, RED);
    wtrans_all<<<dim3(4,16,DEPTH),  256, 0, stream>>>(wg,    WTg,   DIM, RED);
    wtrans_all<<<dim3(16,4,DEPTH),  256, 0, stream>>>(wc,    WTc,   RED, DIM);

    copyf4_kernel<<<XELEMS/1024, 256, 0, stream>>>((const float4*)x_in, (float4*)XA);

    for (int l = 0; l < DEPTH; ++l) {
        // ---- attention block ----
        ln_kernel<<<ROWS/4, 256, 0, stream>>>(XA, ln1_g + l*DIM, ln1_b + l*DIM, L, ROWS);
        gemm_db<128,128,32,2,2><<<dim3(64,12), 256, 0, stream>>>(
            L, WTqkv + (size_t)l*DIM*3*DIM, nullptr, nullptr, Q, ROWS, 3*DIM, DIM, 0, 0);
        attn_mfma<<<BB*PP*HEADS, 256, 0, stream>>>(Q, L);
        gemm_db<64,128,64,2,2><<<dim3(128,4), 256, 0, stream>>>(
            L, WTo + (size_t)l*DIM*DIM, b_o + l*DIM, XA, XB, ROWS, DIM, DIM, 0, 1);

        // ---- MLP ----
        ln_kernel<<<ROWS/4, 256, 0, stream>>>(XB, ln2_g + l*DIM, ln2_b + l*DIM, Q, ROWS);
        gemm_db<128,128,32,2,2><<<dim3(64,16), 256, 0, stream>>>(
            Q, WT1 + (size_t)l*DIM*MLPD, b1 + l*MLPD, nullptr, H, ROWS, MLPD, DIM, 1, 0);
        gemm_db<64,128,64,2,2><<<dim3(128,4), 256, 0, stream>>>(
            H, WT2 + (size_t)l*MLPD*DIM, b2 + l*DIM, nullptr, M1, ROWS, DIM, MLPD, 0, 1);

        // ---- BiAttn ----
        ln_kernel<<<ROWS/4, 256, 0, stream>>>(M1, bn_g + l*DIM, bn_b + l*DIM, L, ROWS);
        mean_kernel<<<(BB*NN*DIM)/1024, 256, 0, stream>>>(L, G);
        gemm_db<64,64,64,2,2><<<dim3(32,2), 256, 0, stream>>>(
            G, WTg + (size_t)l*DIM*RED, bg + l*RED, nullptr, G2, BB*NN, RED, DIM, 1, 0);
        gemm_db<64,64,64,2,2><<<dim3(128,2), 256, 0, stream>>>(
            L, WTl + (size_t)l*DIM*RED, bl + l*RED, nullptr, XL, ROWS, RED, DIM, 1, 0);
        gemm_db<64,64,64,2,2><<<dim3(32,8), 256, 0, stream>>>(
            G2, WTc + (size_t)l*RED*DIM, bc + l*DIM, nullptr, CA, BB*NN, DIM, RED, 2, 0);
        sattn_kernel<<<ROWS/4, 256, 0, stream>>>(XL, G2, wsw + (size_t)l*2*RED, bsb + l, S);
        fuse_kernel<<<XELEMS/1024, 256, 0, stream>>>((const float4*)XB, (const float4*)M1,
                                                     CA, S, (float4*)XA);
    }

    copyf4_kernel<<<XELEMS/1024, 256, 0, stream>>>((const float4*)XA, (float4*)d_out);
}